// Round 9
// baseline (497.311 us; speedup 1.0000x reference)
//
#include <hip/hip_runtime.h>

#define H 64
#define N_STAY 200000
#define N_PAT  100000
#define N_EDGE 1000000
#define NBC_STAY 98    // ceil(200000/2048)
#define NBC_PAT  49    // ceil(100000/2048)
#define PB 245         // ceil(1e6/4096) edge blocks of 4096

#define SB2_STAY 1563  // ceil(200000/128) 512-thread blocks
#define SB2_PAT  782   // ceil(100000/128)

typedef unsigned short ushort_t;
typedef __attribute__((ext_vector_type(8))) short bf16x8;
typedef __attribute__((ext_vector_type(4))) float f32x4;
typedef __attribute__((ext_vector_type(2))) float f32x2;

__device__ __forceinline__ float bf2f(ushort_t u) {
  union { unsigned int i; float f; } c;
  c.i = ((unsigned int)u) << 16;
  return c.f;
}
__device__ __forceinline__ unsigned int f2bf_bits(float f) {
  union { float v; unsigned int i; } c; c.v = f;
  unsigned int r = c.i + 0x7fffu + ((c.i >> 16) & 1u);  // RNE
  return r >> 16;
}
__device__ __forceinline__ bf16x8 ld_frag(const ushort_t* p) {
  union { uint4 u; bf16x8 v; } c;
  c.u = *(const uint4*)p;
  return c.v;
}

// ---- agg helpers -----------------------------------------------------------

__device__ __forceinline__ f32x2 upk2(unsigned int u) {
  f32x2 r;
  r.x = __uint_as_float(u << 16);
  r.y = __uint_as_float(u & 0xffff0000u);
  return r;
}
__device__ __forceinline__ void fma2(f32x2& a, unsigned int u, float w) {
  a.x = fmaf(__uint_as_float(u << 16), w, a.x);
  a.y = fmaf(__uint_as_float(u & 0xffff0000u), w, a.y);
}
__device__ __forceinline__ unsigned int cvtpk_bf16(float lo, float hi) {
  unsigned int r;
  asm("v_cvt_pk_bf16_f32 %0, %1, %2" : "=v"(r) : "v"(lo), "v"(hi));
  return r;
}

// ---------------- CSR build -------------------------------------------------

__global__ __launch_bounds__(256)
void blockhist3_kernel(const int* __restrict__ d1, const int* __restrict__ d2,
                       const int* __restrict__ d3,
                       int* __restrict__ h1, int* __restrict__ h2, int* __restrict__ h3) {
  int which = blockIdx.x / PB;
  int blk = blockIdx.x % PB;
  const int* dp = (which == 0) ? d1 : (which == 1) ? d2 : d3;
  int* hp = (which == 0) ? h1 : (which == 1) ? h2 : h3;
  int nbc = (which == 0) ? NBC_PAT : NBC_STAY;
  __shared__ int lh[128];
  if (threadIdx.x < 128) lh[threadIdx.x] = 0;
  __syncthreads();
  int base = blk * 4096;
  int n = min(4096, N_EDGE - base);
  for (int i = threadIdx.x; i < n; i += 256)
    atomicAdd(&lh[dp[base + i] >> 11], 1);
  __syncthreads();
  if (threadIdx.x < nbc && lh[threadIdx.x])
    atomicAdd(&hp[threadIdx.x], lh[threadIdx.x]);
}

// single-block exclusive scan body, n <= 4096; writes off[0..n] and cur[0..n-1]
__device__ __forceinline__
void scan_dev(const int* __restrict__ in, int n, int* __restrict__ off,
              int* __restrict__ cur, int total) {
  int tid = threadIdx.x;
  int base = tid * 16;
  int vals[16]; int s = 0;
  #pragma unroll
  for (int i = 0; i < 16; ++i) {
    int idx = base + i;
    vals[i] = (idx < n) ? in[idx] : 0;
    s += vals[i];
  }
  int lane = tid & 63, w = tid >> 6;
  int incl = s;
  #pragma unroll
  for (int o = 1; o < 64; o <<= 1) {
    int t = __shfl_up(incl, o);
    if (lane >= o) incl += t;
  }
  __shared__ int wtot[4];
  if (lane == 63) wtot[w] = incl;
  __syncthreads();
  int wbase = 0;
  for (int i = 0; i < w; ++i) wbase += wtot[i];
  int run = wbase + incl - s;
  #pragma unroll
  for (int i = 0; i < 16; ++i) {
    int idx = base + i;
    if (idx < n) { off[idx] = run; cur[idx] = run; run += vals[i]; }
  }
  if (tid == 0) off[n] = total;
}

// three coarse-hist scans in one dispatch (block = which)
__global__ __launch_bounds__(256)
void scan3_kernel(const int* __restrict__ bh1, int* __restrict__ bo1, int* __restrict__ bc1,
                  const int* __restrict__ bh2, int* __restrict__ bo2, int* __restrict__ bc2,
                  const int* __restrict__ bh3, int* __restrict__ bo3, int* __restrict__ bc3) {
  if (blockIdx.x == 0)      scan_dev(bh1, NBC_PAT,  bo1, bc1, N_EDGE);
  else if (blockIdx.x == 1) scan_dev(bh2, NBC_STAY, bo2, bc2, N_EDGE);
  else                      scan_dev(bh3, NBC_STAY, bo3, bc3, N_EDGE);
}

// packed value = src | ((dst & 2047) << 18); bucket = dst >> 11
__global__ __launch_bounds__(256)
void phaseA3_kernel(const int* __restrict__ s1, const int* __restrict__ d1,
                    const int* __restrict__ s2, const int* __restrict__ d2,
                    const int* __restrict__ s3, const int* __restrict__ d3,
                    int* __restrict__ c1, int* __restrict__ c2, int* __restrict__ c3,
                    int* __restrict__ v1, int* __restrict__ v2, int* __restrict__ v3) {
  int which = blockIdx.x / PB;
  int blk = blockIdx.x % PB;
  const int* sp = (which == 0) ? s1 : (which == 1) ? s2 : s3;
  const int* dp = (which == 0) ? d1 : (which == 1) ? d2 : d3;
  int* cp = (which == 0) ? c1 : (which == 1) ? c2 : c3;
  int* vp = (which == 0) ? v1 : (which == 1) ? v2 : v3;
  int nbc = (which == 0) ? NBC_PAT : NBC_STAY;
  __shared__ int vals[4096];
  __shared__ unsigned char bkt[4096];
  __shared__ int lh[128], lbase[128], lcur[128], gbase[128];
  __shared__ int wt[2];
  const int tid = threadIdx.x;
  if (tid < 128) lh[tid] = 0;
  __syncthreads();
  int base = blk * 4096;
  int n = min(4096, N_EDGE - base);
  int pv[16], pbk[16];
  #pragma unroll
  for (int i = 0; i < 16; ++i) {
    int idx = i * 256 + tid;
    if (idx < n) {
      int e = base + idx;
      int d = dp[e], s = sp[e];
      pv[i] = s | ((d & 2047) << 18);
      pbk[i] = d >> 11;
      atomicAdd(&lh[pbk[i]], 1);
    } else pbk[i] = -1;
  }
  __syncthreads();
  // exclusive scan of lh[0..nbc) (nbc <= 98 < 128) via two waves
  {
    int lane = tid & 63, w = tid >> 6;
    int x = (tid < 128 && tid < nbc) ? lh[tid] : 0;
    int incl = x;
    #pragma unroll
    for (int o = 1; o < 64; o <<= 1) {
      int t = __shfl_up(incl, o);
      if (lane >= o) incl += t;
    }
    if (w < 2 && lane == 63) wt[w] = incl;
    __syncthreads();
    if (tid < 128) {
      int ex = incl - x + ((w == 1) ? wt[0] : 0);
      lbase[tid] = ex;
      lcur[tid] = ex;
    }
  }
  __syncthreads();
  // place into LDS sorted by bucket
  #pragma unroll
  for (int i = 0; i < 16; ++i) {
    if (pbk[i] >= 0) {
      int r = atomicAdd(&lcur[pbk[i]], 1);
      vals[r] = pv[i];
      bkt[r] = (unsigned char)pbk[i];
    }
  }
  __syncthreads();
  // reserve global space: one atomic per non-empty bucket group
  if (tid < nbc) {
    int cnt = lh[tid];
    gbase[tid] = cnt ? atomicAdd(&cp[tid], cnt) : 0;
  }
  __syncthreads();
  // contiguous run copy-out (consecutive i -> mostly consecutive addresses)
  for (int i = tid; i < n; i += 256) {
    int b = bkt[i];
    vp[gbase[b] + i - lbase[b]] = vals[i];
  }
}

// one block per coarse bucket: node-sorted csr + off[]
__global__ __launch_bounds__(256)
void phaseB3_kernel(const int* __restrict__ v1, const int* __restrict__ bo1,
                    const int* __restrict__ v2, const int* __restrict__ bo2,
                    const int* __restrict__ v3, const int* __restrict__ bo3,
                    int* __restrict__ csr1, int* __restrict__ off1,
                    int* __restrict__ csr2, int* __restrict__ off2,
                    int* __restrict__ csr3, int* __restrict__ off3) {
  int b = blockIdx.x;
  const int* v; const int* bo; int* csr; int* off; int N; int lb;
  if (b < NBC_PAT)                 { v = v1; bo = bo1; csr = csr1; off = off1; N = N_PAT;  lb = b; }
  else if (b < NBC_PAT + NBC_STAY) { v = v2; bo = bo2; csr = csr2; off = off2; N = N_STAY; lb = b - NBC_PAT; }
  else                             { v = v3; bo = bo3; csr = csr3; off = off3; N = N_STAY; lb = b - NBC_PAT - NBC_STAY; }
  const int tid = threadIdx.x;
  __shared__ int lh[2048];
  __shared__ int lcur[2048];
  __shared__ int wt[4];
  #pragma unroll
  for (int j = 0; j < 8; ++j) lh[tid + j * 256] = 0;
  __syncthreads();
  const int rb = bo[lb], re = bo[lb + 1];
  for (int i = rb + tid; i < re; i += 256)
    atomicAdd(&lh[(v[i] >> 18) & 2047], 1);
  __syncthreads();
  // block exclusive scan over 2048 -> lcur (+rb), emit off[]
  const int node_base = lb * 2048;
  const int b8 = tid * 8;
  int ex[8]; int run = 0;
  #pragma unroll
  for (int j = 0; j < 8; ++j) { ex[j] = run; run += lh[b8 + j]; }
  int lane = tid & 63, w = tid >> 6;
  int incl = run;
  #pragma unroll
  for (int o = 1; o < 64; o <<= 1) {
    int t = __shfl_up(incl, o);
    if (lane >= o) incl += t;
  }
  if (lane == 63) wt[w] = incl;
  __syncthreads();
  int wb = 0;
  for (int i = 0; i < w; ++i) wb += wt[i];
  const int tex = rb + wb + incl - run;
  #pragma unroll
  for (int j = 0; j < 8; ++j) {
    int pos = tex + ex[j];
    lcur[b8 + j] = pos;
    int node = node_base + b8 + j;
    if (node < N) off[node] = pos;
  }
  __syncthreads();
  for (int i = rb + tid; i < re; i += 256) {
    int val = v[i];
    int pos = atomicAdd(&lcur[(val >> 18) & 2047], 1);
    csr[pos] = val & 0x3FFFF;
  }
  if (b == 0 && tid == 0) {
    off1[N_PAT] = N_EDGE;
    off2[N_STAY] = N_EDGE;
    off3[N_STAY] = N_EDGE;
  }
}

// ---------------- weight preconversion to MFMA B-fragments (hi+lo bf16) -----

template<int K>
__device__ __forceinline__
void precvt_dev(const float* __restrict__ src, ushort_t* __restrict__ dst,
                int nmat, int blk) {
  const int KS = K / 32;
  const int FU = KS * 4;
  const int PLANE = FU * 64 * 8;
  int fu = blk * 4 + (threadIdx.x >> 6);
  int lane = threadIdx.x & 63;
  int mi = fu / FU;
  if (mi >= nmat) return;
  int fid = fu % FU;
  int ntile = fid / KS;
  int kstep = fid % KS;
  int q = lane >> 4, n = ntile * 16 + (lane & 15);
  const float* W = src + (size_t)mi * K * H;
  union { ushort_t s[8]; uint4 u; } hi, lo;
  #pragma unroll
  for (int j = 0; j < 8; ++j) {
    float v = W[(size_t)(kstep * 32 + q * 8 + j) * H + n];
    unsigned hb = f2bf_bits(v);
    hi.s[j] = (ushort_t)hb;
    lo.s[j] = (ushort_t)f2bf_bits(v - bf2f((ushort_t)hb));
  }
  ushort_t* base = dst + (size_t)mi * 2 * PLANE + ((size_t)fid * 64 + lane) * 8;
  *(uint4*)base = hi.u;
  *(uint4*)(base + PLANE) = lo.u;
}

// blocks [0,4)=WpS, [4,6)=WpP, [6,18)=Wl (6 mats), [18,30)=Wr (6 mats)
__global__ __launch_bounds__(256)
void precvt_all_kernel(const float* __restrict__ WpS, const float* __restrict__ WpP,
                       const float* __restrict__ Wl, const float* __restrict__ Wr,
                       ushort_t* __restrict__ fWpS, ushort_t* __restrict__ fWpP,
                       ushort_t* __restrict__ fWlB, ushort_t* __restrict__ fWrB) {
  int b = blockIdx.x;
  if (b < 4)        precvt_dev<128>(WpS, fWpS, 1, b);
  else if (b < 6)   precvt_dev<64>(WpP, fWpP, 1, b - 4);
  else if (b < 18)  precvt_dev<64>(Wl, fWlB, 6, b - 6);
  else              precvt_dev<64>(Wr, fWrB, 6, b - 18);
}

// ---------------- fused aggregation: 8 lanes per node, 8 nodes per wave ------
// 4-deep unroll into 2 accumulator sets (rows 1..3 of each quad masked by fma
// weight): 4 independent row loads in flight per group, half the trip count.

__global__ __launch_bounds__(256)
void agg_all_kernel(const ushort_t* __restrict__ hs, const ushort_t* __restrict__ hp,
                    const int* __restrict__ off1, const int* __restrict__ csr1,
                    const int* __restrict__ off2, const int* __restrict__ csr2,
                    const int* __restrict__ off3, const int* __restrict__ csr3,
                    ushort_t* __restrict__ agg1, ushort_t* __restrict__ agg2,
                    ushort_t* __restrict__ agg3) {
  const int wid = __builtin_amdgcn_readfirstlane(threadIdx.x >> 6);
  int nb = (blockIdx.x * 4 + wid) * 8;   // first node of this wave (scalar)
  const ushort_t* x; const int* off; const int* csr; ushort_t* out;
  if (nb < N_PAT) {
    x = hs; off = off1; csr = csr1; out = agg1;
  } else if (nb < N_PAT + N_STAY) {
    nb -= N_PAT;            x = hp; off = off2; csr = csr2; out = agg2;
  } else if (nb < N_PAT + 2 * N_STAY) {
    nb -= N_PAT + N_STAY;   x = hs; off = off3; csr = csr3; out = agg3;
  } else return;
  const int lane = threadIdx.x & 63;
  const int g = lane >> 3;           // node group within wave
  const int fg = lane & 7;           // 16B chunk within the 128B row
  const int node = nb + g;
  const int o0 = off[node], o1 = off[node + 1];
  const char* xb = (const char*)x + (fg << 4);
  f32x2 a0 = {0.f,0.f}, a1 = {0.f,0.f}, a2 = {0.f,0.f}, a3 = {0.f,0.f};
  f32x2 b0 = {0.f,0.f}, b1 = {0.f,0.f}, b2 = {0.f,0.f}, b3 = {0.f,0.f};
  int t = o0;
  int s0 = (t     < o1) ? csr[t]     : 0;
  int s1 = (t + 1 < o1) ? csr[t + 1] : 0;
  int s2 = (t + 2 < o1) ? csr[t + 2] : 0;
  int s3 = (t + 3 < o1) ? csr[t + 3] : 0;
  while (t < o1) {
    uint4 qa = *(const uint4*)(xb + ((unsigned)s0 << 7));
    uint4 qb = *(const uint4*)(xb + ((unsigned)s1 << 7));
    uint4 qc = *(const uint4*)(xb + ((unsigned)s2 << 7));
    uint4 qd = *(const uint4*)(xb + ((unsigned)s3 << 7));
    const float w1 = (t + 1 < o1) ? 1.0f : 0.0f;
    const float w2 = (t + 2 < o1) ? 1.0f : 0.0f;
    const float w3 = (t + 3 < o1) ? 1.0f : 0.0f;
    int t4 = t + 4;
    s0 = (t4     < o1) ? csr[t4]     : 0;
    s1 = (t4 + 1 < o1) ? csr[t4 + 1] : 0;
    s2 = (t4 + 2 < o1) ? csr[t4 + 2] : 0;
    s3 = (t4 + 3 < o1) ? csr[t4 + 3] : 0;
    a0 += upk2(qa.x); a1 += upk2(qa.y); a2 += upk2(qa.z); a3 += upk2(qa.w);
    fma2(b0, qb.x, w1); fma2(b1, qb.y, w1); fma2(b2, qb.z, w1); fma2(b3, qb.w, w1);
    fma2(a0, qc.x, w2); fma2(a1, qc.y, w2); fma2(a2, qc.z, w2); fma2(a3, qc.w, w2);
    fma2(b0, qd.x, w3); fma2(b1, qd.y, w3); fma2(b2, qd.z, w3); fma2(b3, qd.w, w3);
    t = t4;
  }
  a0 += b0; a1 += b1; a2 += b2; a3 += b3;
  const float inv = __builtin_amdgcn_rcpf(fmaxf((float)(o1 - o0), 1.0f));
  uint4 q;
  q.x = cvtpk_bf16(a0.x * inv, a0.y * inv);
  q.y = cvtpk_bf16(a1.x * inv, a1.y * inv);
  q.z = cvtpk_bf16(a2.x * inv, a2.y * inv);
  q.w = cvtpk_bf16(a3.x * inv, a3.y * inv);
  *(uint4*)(out + (size_t)node * H + fg * 8) = q;   // wave stores 1KB contiguous
}

// ---------------- MFMA dense kernels ----------------------------------------

#define MFMA16(a, b, c) __builtin_amdgcn_mfma_f32_16x16x32_bf16((a), (b), (c), 0, 0, 0)

// proj with weight fragments staged in LDS; 512-thread blocks, 128 rows/block.
// R9: ALL x-loads hoisted into registers before any convert/MFMA -- proj is
// the only cold-HBM reader (x touched once); MLP per wave goes 2 -> 2*KS so
// one latency stall instead of KS.
template<int K>
__device__ __forceinline__
void proj_lds_dev(const float* __restrict__ x, const ushort_t* __restrict__ fw,
                  const float* __restrict__ b, ushort_t* __restrict__ y,
                  int N, int blk, uint4* __restrict__ u4) {
  const int KS = K / 32;
  const int PLANE = KS * 4 * 64 * 8;       // ushorts per plane
  const int NU4 = PLANE / 4;               // uint4 count covering both planes
  const int tid = threadIdx.x;
  for (int i = tid; i < NU4; i += 512)
    u4[i] = ((const uint4*)fw)[i];
  const int wid = tid >> 6, lane = tid & 63;
  const int r0 = blk * 128 + wid * 16;
  const int m = lane & 15, q = lane >> 4;
  // issue ALL x loads before the staging barrier (independent of LDS)
  float4 xv[2 * KS];
  if (r0 < N) {
    const float* xr = x + (size_t)(r0 + m) * K + q * 8;
    #pragma unroll
    for (int ks = 0; ks < KS; ++ks) {
      xv[2 * ks]     = *(const float4*)(xr + ks * 32);
      xv[2 * ks + 1] = *(const float4*)(xr + ks * 32 + 4);
    }
  }
  __syncthreads();
  if (r0 >= N) return;                     // after the barrier: safe
  const ushort_t* w = (const ushort_t*)u4;
  f32x4 c[4] = {{0,0,0,0},{0,0,0,0},{0,0,0,0},{0,0,0,0}};
  #pragma unroll
  for (int ks = 0; ks < KS; ++ks) {
    float4 v0 = xv[2 * ks];
    float4 v1 = xv[2 * ks + 1];
    float vv[8] = {v0.x, v0.y, v0.z, v0.w, v1.x, v1.y, v1.z, v1.w};
    union { ushort_t s[8]; bf16x8 v; } ah, al;
    #pragma unroll
    for (int j = 0; j < 8; ++j) {
      unsigned hb = f2bf_bits(vv[j]);
      ah.s[j] = (ushort_t)hb;
      al.s[j] = (ushort_t)f2bf_bits(vv[j] - bf2f((ushort_t)hb));
    }
    #pragma unroll
    for (int nt = 0; nt < 4; ++nt) {
      const ushort_t* fb = w + ((size_t)(nt * KS + ks) * 64 + lane) * 8;
      bf16x8 bh = ld_frag(fb);
      bf16x8 blo = ld_frag(fb + PLANE);
      c[nt] = MFMA16(ah.v, bh, c[nt]);
      c[nt] = MFMA16(ah.v, blo, c[nt]);
      c[nt] = MFMA16(al.v, bh, c[nt]);
    }
  }
  #pragma unroll
  for (int nt = 0; nt < 4; ++nt) {
    float bias = b[nt * 16 + m];
    #pragma unroll
    for (int r = 0; r < 4; ++r) {
      float o = fmaxf(c[nt][r] + bias, 0.0f);
      y[(size_t)(r0 + q * 4 + r) * H + nt * 16 + m] = (ushort_t)f2bf_bits(o);
    }
  }
}

// both projections in one dispatch: blocks [0,SB2_STAY)=stay K=128, rest pat K=64
__global__ __launch_bounds__(512)
void proj_both_kernel(const float* __restrict__ xs, const ushort_t* __restrict__ fws,
                      const float* __restrict__ bs,
                      const float* __restrict__ xp, const ushort_t* __restrict__ fwp,
                      const float* __restrict__ bp,
                      ushort_t* __restrict__ ys, ushort_t* __restrict__ yp) {
  __shared__ uint4 u4[2048];   // 32KB
  if (blockIdx.x < SB2_STAY) proj_lds_dev<128>(xs, fws, bs, ys, N_STAY, blockIdx.x, u4);
  else                       proj_lds_dev<64>(xp, fwp, bp, yp, N_PAT, blockIdx.x - SB2_STAY, u4);
}

// ---------------- fused SAGE layer: stay + pat in ONE dispatch ---------------
// 512-thread blocks (128 rows). HI-PLANE-ONLY weights (verified R8: absmax
// 0.0137 vs 0.0323 threshold). final!=0: stay-side computes regression head.

__global__ __launch_bounds__(512)
void sage_both_mfma(const ushort_t* __restrict__ agg1, const ushort_t* __restrict__ xp_in,
                    const ushort_t* __restrict__ agg2, const ushort_t* __restrict__ agg3,
                    const ushort_t* __restrict__ xs_in,
                    const ushort_t* __restrict__ fWl0, const ushort_t* __restrict__ fWr0,
                    const ushort_t* __restrict__ fWl1, const ushort_t* __restrict__ fWr1,
                    const ushort_t* __restrict__ fWl2, const ushort_t* __restrict__ fWr2,
                    const float* __restrict__ bl0, const float* __restrict__ bl1,
                    const float* __restrict__ bl2,
                    const float* __restrict__ g, const float* __restrict__ bb,
                    ushort_t* __restrict__ out_p, ushort_t* __restrict__ out_s,
                    const float* __restrict__ Wreg, const float* __restrict__ breg,
                    float* __restrict__ reg_out, int final_l) {
  __shared__ uint4 u4[2048];   // 32KB (hi planes only: 4 x 512 uint4)
  ushort_t* w = (ushort_t*)u4;
  const int tid = threadIdx.x;
  const int wid = tid >> 6, lane = tid & 63;
  const int m = lane & 15, q = lane >> 4;

  if (blockIdx.x < SB2_STAY) {
    // ---------------- stay side ----------------
    u4[tid]          = ((const uint4*)fWl1)[tid];
    u4[512  + tid]   = ((const uint4*)fWr1)[tid];
    u4[1024 + tid]   = ((const uint4*)fWl2)[tid];
    u4[1536 + tid]   = ((const uint4*)fWr2)[tid];
    __syncthreads();
    const int r0 = blockIdx.x * 128 + wid * 16;
    if (r0 >= N_STAY) return;    // after the barrier: safe
    const ushort_t* lWl1 = w;            // 4096 ushorts each
    const ushort_t* lWr1 = w + 4096;
    const ushort_t* lWl2 = w + 8192;
    const ushort_t* lWr2 = w + 12288;
    const ushort_t* a2p = agg2 + (size_t)(r0 + m) * H + q * 8;
    const ushort_t* a3p = agg3 + (size_t)(r0 + m) * H + q * 8;
    const ushort_t* xp  = xs_in + (size_t)(r0 + m) * H + q * 8;
    bf16x8 A2[2], A3[2], X[2];
    A2[0] = ld_frag(a2p); A2[1] = ld_frag(a2p + 32);
    A3[0] = ld_frag(a3p); A3[1] = ld_frag(a3p + 32);
    X[0]  = ld_frag(xp);  X[1]  = ld_frag(xp + 32);
    f32x4 c2[4] = {{0,0,0,0},{0,0,0,0},{0,0,0,0},{0,0,0,0}};
    f32x4 c3[4] = {{0,0,0,0},{0,0,0,0},{0,0,0,0},{0,0,0,0}};
    #pragma unroll
    for (int nt = 0; nt < 4; ++nt) {
      #pragma unroll
      for (int ks = 0; ks < 2; ++ks) {
        const size_t fo = ((size_t)(nt * 2 + ks) * 64 + lane) * 8;
        bf16x8 bh = ld_frag(lWl1 + fo);
        c2[nt] = MFMA16(A2[ks], bh, c2[nt]);
        bh = ld_frag(lWr1 + fo);
        c2[nt] = MFMA16(X[ks], bh, c2[nt]);
        bh = ld_frag(lWl2 + fo);
        c3[nt] = MFMA16(A3[ks], bh, c3[nt]);
        bh = ld_frag(lWr2 + fo);
        c3[nt] = MFMA16(X[ks], bh, c3[nt]);
      }
    }
    float n2s[4] = {0,0,0,0}, n3s[4] = {0,0,0,0};
    #pragma unroll
    for (int nt = 0; nt < 4; ++nt) {
      float b2 = bl1[nt * 16 + m], b3 = bl2[nt * 16 + m];
      #pragma unroll
      for (int r = 0; r < 4; ++r) {
        c2[nt][r] += b2;
        c3[nt][r] += b3;
        n2s[r] = fmaf(c2[nt][r], c2[nt][r], n2s[r]);
        n3s[r] = fmaf(c3[nt][r], c3[nt][r], n3s[r]);
      }
    }
    #pragma unroll
    for (int off = 1; off < 16; off <<= 1)
      #pragma unroll
      for (int r = 0; r < 4; ++r) {
        n2s[r] += __shfl_xor(n2s[r], off);
        n3s[r] += __shfl_xor(n3s[r], off);
      }
    float r2v[4], r3v[4];
    #pragma unroll
    for (int r = 0; r < 4; ++r) {
      r2v[r] = 0.5f / fmaxf(sqrtf(n2s[r]), 1e-12f);
      r3v[r] = 0.5f / fmaxf(sqrtf(n3s[r]), 1e-12f);
    }
    float y[4][4];
    float s1[4] = {0,0,0,0}, s2[4] = {0,0,0,0};
    #pragma unroll
    for (int nt = 0; nt < 4; ++nt)
      #pragma unroll
      for (int r = 0; r < 4; ++r) {
        float v = fmaxf(fmaf(c2[nt][r], r2v[r], c3[nt][r] * r3v[r]), 0.0f);
        y[nt][r] = v;
        s1[r] += v;
        s2[r] = fmaf(v, v, s2[r]);
      }
    #pragma unroll
    for (int off = 1; off < 16; off <<= 1)
      #pragma unroll
      for (int r = 0; r < 4; ++r) {
        s1[r] += __shfl_xor(s1[r], off);
        s2[r] += __shfl_xor(s2[r], off);
      }
    float mean[4], sig[4];
    #pragma unroll
    for (int r = 0; r < 4; ++r) {
      mean[r] = s1[r] * (1.0f / H);
      float var = s2[r] * (1.0f / H) - mean[r] * mean[r];
      sig[r] = rsqrtf(var + 1e-5f);
    }
    unsigned int obits[4][4];
    #pragma unroll
    for (int nt = 0; nt < 4; ++nt) {
      float gv = g[nt * 16 + m], bv = bb[nt * 16 + m];
      #pragma unroll
      for (int r = 0; r < 4; ++r) {
        float o = (y[nt][r] - mean[r]) * sig[r] * gv + bv;
        obits[nt][r] = f2bf_bits(o);
        out_s[(size_t)(r0 + q * 4 + r) * H + nt * 16 + m] = (ushort_t)obits[nt][r];
      }
    }
    if (final_l) {
      float wv[4];
      #pragma unroll
      for (int nt = 0; nt < 4; ++nt) wv[nt] = Wreg[nt * 16 + m];
      float p[4] = {0,0,0,0};
      #pragma unroll
      for (int nt = 0; nt < 4; ++nt)
        #pragma unroll
        for (int r = 0; r < 4; ++r)
          p[r] = fmaf(bf2f((ushort_t)obits[nt][r]), wv[nt], p[r]);
      #pragma unroll
      for (int off = 1; off < 16; off <<= 1)
        #pragma unroll
        for (int r = 0; r < 4; ++r) p[r] += __shfl_xor(p[r], off);
      if (m == 0) {
        float b0v = breg[0];
        #pragma unroll
        for (int r = 0; r < 4; ++r) reg_out[r0 + q * 4 + r] = p[r] + b0v;
      }
    }
  } else {
    // ---------------- pat side ----------------
    u4[tid]       = ((const uint4*)fWl0)[tid];
    u4[512 + tid] = ((const uint4*)fWr0)[tid];
    __syncthreads();
    const int r0 = (blockIdx.x - SB2_STAY) * 128 + wid * 16;
    if (r0 >= N_PAT) return;   // after the barrier: safe
    const ushort_t* lWl0 = w;
    const ushort_t* lWr0 = w + 4096;
    const ushort_t* ap = agg1 + (size_t)(r0 + m) * H + q * 8;
    const ushort_t* xp = xp_in + (size_t)(r0 + m) * H + q * 8;
    bf16x8 A[2], X[2];
    A[0] = ld_frag(ap); A[1] = ld_frag(ap + 32);
    X[0] = ld_frag(xp); X[1] = ld_frag(xp + 32);
    f32x4 c[4] = {{0,0,0,0},{0,0,0,0},{0,0,0,0},{0,0,0,0}};
    #pragma unroll
    for (int nt = 0; nt < 4; ++nt) {
      #pragma unroll
      for (int ks = 0; ks < 2; ++ks) {
        const size_t fo = ((size_t)(nt * 2 + ks) * 64 + lane) * 8;
        bf16x8 bh = ld_frag(lWl0 + fo);
        c[nt] = MFMA16(A[ks], bh, c[nt]);
        bh = ld_frag(lWr0 + fo);
        c[nt] = MFMA16(X[ks], bh, c[nt]);
      }
    }
    float n2s[4] = {0, 0, 0, 0};
    #pragma unroll
    for (int nt = 0; nt < 4; ++nt) {
      float bias = bl0[nt * 16 + m];
      #pragma unroll
      for (int r = 0; r < 4; ++r) {
        c[nt][r] += bias;
        n2s[r] = fmaf(c[nt][r], c[nt][r], n2s[r]);
      }
    }
    #pragma unroll
    for (int off = 1; off < 16; off <<= 1)
      #pragma unroll
      for (int r = 0; r < 4; ++r) n2s[r] += __shfl_xor(n2s[r], off);
    float rv[4];
    #pragma unroll
    for (int r = 0; r < 4; ++r) rv[r] = 1.0f / fmaxf(sqrtf(n2s[r]), 1e-12f);
    float y[4][4];
    float s1[4] = {0,0,0,0}, s2[4] = {0,0,0,0};
    #pragma unroll
    for (int nt = 0; nt < 4; ++nt)
      #pragma unroll
      for (int r = 0; r < 4; ++r) {
        float v = fmaxf(c[nt][r] * rv[r], 0.0f);
        y[nt][r] = v;
        s1[r] += v;
        s2[r] = fmaf(v, v, s2[r]);
      }
    #pragma unroll
    for (int off = 1; off < 16; off <<= 1)
      #pragma unroll
      for (int r = 0; r < 4; ++r) {
        s1[r] += __shfl_xor(s1[r], off);
        s2[r] += __shfl_xor(s2[r], off);
      }
    float mean[4], sig[4];
    #pragma unroll
    for (int r = 0; r < 4; ++r) {
      mean[r] = s1[r] * (1.0f / H);
      float var = s2[r] * (1.0f / H) - mean[r] * mean[r];
      sig[r] = rsqrtf(var + 1e-5f);
    }
    #pragma unroll
    for (int nt = 0; nt < 4; ++nt) {
      float gv = g[nt * 16 + m], bv = bb[nt * 16 + m];
      #pragma unroll
      for (int r = 0; r < 4; ++r) {
        float o = (y[nt][r] - mean[r]) * sig[r] * gv + bv;
        out_p[(size_t)(r0 + q * 4 + r) * H + nt * 16 + m] = (ushort_t)f2bf_bits(o);
      }
    }
  }
}

// -----------------------------------------------------------------------------

extern "C" void kernel_launch(void* const* d_in, const int* in_sizes, int n_in,
                              void* d_out, int out_size, void* d_ws, size_t ws_size,
                              hipStream_t stream) {
  const float* x_stay  = (const float*)d_in[0];
  const float* x_pat   = (const float*)d_in[1];
  const float* Wp_stay = (const float*)d_in[2];
  const float* bp_stay = (const float*)d_in[3];
  const float* Wp_pat  = (const float*)d_in[4];
  const float* bp_pat  = (const float*)d_in[5];
  const float* Wl      = (const float*)d_in[6];
  const float* bl      = (const float*)d_in[7];
  const float* Wr      = (const float*)d_in[8];
  const float* ln_g    = (const float*)d_in[9];
  const float* ln_b    = (const float*)d_in[10];
  const float* Wreg    = (const float*)d_in[11];
  const float* breg    = (const float*)d_in[12];
  const int* e1s = (const int*)d_in[13];
  const int* e1d = (const int*)d_in[14];
  const int* e2s = (const int*)d_in[15];
  const int* e2d = (const int*)d_in[16];
  const int* e3s = (const int*)d_in[17];
  const int* e3d = (const int*)d_in[18];
  float* out = (float*)d_out;

  const size_t S = (size_t)N_STAY * H;
  const size_t P = (size_t)N_PAT * H;

  ushort_t* hs   = (ushort_t*)d_ws;
  ushort_t* hp   = hs + S;
  ushort_t* agg1 = hp + P;
  ushort_t* agg2 = agg1 + P;
  ushort_t* agg3 = agg2 + S;
  ushort_t* fragW = agg3 + S;
  ushort_t* fWpS = fragW;                // K=128: 2*8192
  ushort_t* fWpP = fragW + 16384;        // K=64:  2*4096
  ushort_t* fWlB = fragW + 24576;        // 6 * 8192
  ushort_t* fWrB = fragW + 24576 + 49152;
  int* ib    = (int*)(fragW + 122880);
  int* off1  = ib;                         // N_PAT+1
  int* off2  = off1 + (N_PAT + 1);         // N_STAY+1
  int* off3  = off2 + (N_STAY + 1);        // N_STAY+1
  int* bh1   = off3 + (N_STAY + 1);        // coarse hists, contiguous
  int* bh2   = bh1 + NBC_PAT;
  int* bh3   = bh2 + NBC_STAY;
  int* bo1   = bh3 + NBC_STAY;             // NBC_PAT+1
  int* bo2   = bo1 + (NBC_PAT + 1);        // NBC_STAY+1
  int* bo3   = bo2 + (NBC_STAY + 1);       // NBC_STAY+1
  int* bc1   = bo3 + (NBC_STAY + 1);       // cursors
  int* bc2   = bc1 + NBC_PAT;
  int* bc3   = bc2 + NBC_STAY;
  int* bv1   = bc3 + NBC_STAY;             // binned packed values, E each
  int* bv2   = bv1 + N_EDGE;
  int* bv3   = bv2 + N_EDGE;
  int* csr1  = bv3 + N_EDGE;               // E each
  int* csr2  = csr1 + N_EDGE;
  int* csr3  = csr2 + N_EDGE;

  // weight preconversion (tiny, one dispatch)
  precvt_all_kernel<<<30, 256, 0, stream>>>(Wp_stay, Wp_pat, Wl, Wr,
                                            fWpS, fWpP, fWlB, fWrB);

  // CSR build (R3-proven structure)
  hipMemsetAsync(bh1, 0, (size_t)(NBC_PAT + 2 * NBC_STAY) * sizeof(int), stream);
  blockhist3_kernel<<<3 * PB, 256, 0, stream>>>(e1d, e2d, e3d, bh1, bh2, bh3);
  scan3_kernel<<<3, 256, 0, stream>>>(bh1, bo1, bc1, bh2, bo2, bc2, bh3, bo3, bc3);
  phaseA3_kernel<<<3 * PB, 256, 0, stream>>>(e1s, e1d, e2s, e2d, e3s, e3d,
                                             bc1, bc2, bc3, bv1, bv2, bv3);
  phaseB3_kernel<<<NBC_PAT + 2 * NBC_STAY, 256, 0, stream>>>(
      bv1, bo1, bv2, bo2, bv3, bo3, csr1, off1, csr2, off2, csr3, off3);

  // input projections (LDS-staged weights, 512-thread blocks, hoisted x-loads)
  proj_both_kernel<<<SB2_STAY + SB2_PAT, 512, 0, stream>>>(
      x_stay, fWpS, bp_stay, x_pat, fWpP, bp_pat, hs, hp);

  // 8 nodes per wave, 4 waves per block
  const int AGG_ALL_BLOCKS = (N_PAT + 2 * N_STAY) / 32;   // 500000/32 = 15625 exact

  for (int l = 0; l < 2; ++l) {
    ushort_t* fWl0 = fWlB + (size_t)(l * 3 + 0) * 8192;
    ushort_t* fWl1 = fWlB + (size_t)(l * 3 + 1) * 8192;
    ushort_t* fWl2 = fWlB + (size_t)(l * 3 + 2) * 8192;
    ushort_t* fWr0 = fWrB + (size_t)(l * 3 + 0) * 8192;
    ushort_t* fWr1 = fWrB + (size_t)(l * 3 + 1) * 8192;
    ushort_t* fWr2 = fWrB + (size_t)(l * 3 + 2) * 8192;
    const float* bl0 = bl + (size_t)(l * 3 + 0) * H;
    const float* bl1 = bl + (size_t)(l * 3 + 1) * H;
    const float* bl2 = bl + (size_t)(l * 3 + 2) * H;
    const float* g  = ln_g + (size_t)l * H;
    const float* bb = ln_b + (size_t)l * H;

    agg_all_kernel<<<AGG_ALL_BLOCKS, 256, 0, stream>>>(
        hs, hp, off1, csr1, off2, csr2, off3, csr3, agg1, agg2, agg3);

    sage_both_mfma<<<SB2_STAY + SB2_PAT, 512, 0, stream>>>(
        agg1, hp, agg2, agg3, hs,
        fWl0, fWr0, fWl1, fWr1, fWl2, fWr2,
        bl0, bl1, bl2, g, bb,
        hp, hs, Wreg, breg, out, (l == 1) ? 1 : 0);
  }
}

// Round 10
// 469.036 us; speedup vs baseline: 1.0603x; 1.0603x over previous
//
#include <hip/hip_runtime.h>

#define H 64
#define N_STAY 200000
#define N_PAT  100000
#define N_EDGE 1000000
#define NBC_STAY 98    // ceil(200000/2048)
#define NBC_PAT  49    // ceil(100000/2048)
#define PB 245         // ceil(1e6/4096) edge blocks of 4096

#define SB2_STAY 1563  // ceil(200000/128) 512-thread blocks
#define SB2_PAT  782   // ceil(100000/128)

typedef unsigned short ushort_t;
typedef __attribute__((ext_vector_type(8))) short bf16x8;
typedef __attribute__((ext_vector_type(4))) float f32x4;
typedef __attribute__((ext_vector_type(2))) float f32x2;

__device__ __forceinline__ float bf2f(ushort_t u) {
  union { unsigned int i; float f; } c;
  c.i = ((unsigned int)u) << 16;
  return c.f;
}
__device__ __forceinline__ unsigned int f2bf_bits(float f) {
  union { float v; unsigned int i; } c; c.v = f;
  unsigned int r = c.i + 0x7fffu + ((c.i >> 16) & 1u);  // RNE
  return r >> 16;
}
__device__ __forceinline__ bf16x8 ld_frag(const ushort_t* p) {
  union { uint4 u; bf16x8 v; } c;
  c.u = *(const uint4*)p;
  return c.v;
}

// ---- agg helpers -----------------------------------------------------------

__device__ __forceinline__ f32x2 upk2(unsigned int u) {
  f32x2 r;
  r.x = __uint_as_float(u << 16);
  r.y = __uint_as_float(u & 0xffff0000u);
  return r;
}
__device__ __forceinline__ void fma2(f32x2& a, unsigned int u, float w) {
  a.x = fmaf(__uint_as_float(u << 16), w, a.x);
  a.y = fmaf(__uint_as_float(u & 0xffff0000u), w, a.y);
}
__device__ __forceinline__ unsigned int cvtpk_bf16(float lo, float hi) {
  unsigned int r;
  asm("v_cvt_pk_bf16_f32 %0, %1, %2" : "=v"(r) : "v"(lo), "v"(hi));
  return r;
}

// gather mean of neighbor rows into one 128B LDS row (8 lanes cooperate,
// lane covers bytes [fg*16, fg*16+16)). Identical math to the old agg kernel
// (4-deep unroll, masked fma tail, rcp mean, cvt_pk pack) -> bitwise-same agg.
__device__ __forceinline__
void gather_row(const ushort_t* __restrict__ x, const int* __restrict__ off,
                const int* __restrict__ csr, int node,
                char* __restrict__ row, int fg) {
  const int o0 = off[node], o1 = off[node + 1];
  const char* xb = (const char*)x + (fg << 4);
  f32x2 a0 = {0.f,0.f}, a1 = {0.f,0.f}, a2 = {0.f,0.f}, a3 = {0.f,0.f};
  f32x2 b0 = {0.f,0.f}, b1 = {0.f,0.f}, b2 = {0.f,0.f}, b3 = {0.f,0.f};
  int t = o0;
  int s0 = (t     < o1) ? csr[t]     : 0;
  int s1 = (t + 1 < o1) ? csr[t + 1] : 0;
  int s2 = (t + 2 < o1) ? csr[t + 2] : 0;
  int s3 = (t + 3 < o1) ? csr[t + 3] : 0;
  while (t < o1) {
    uint4 qa = *(const uint4*)(xb + ((unsigned)s0 << 7));
    uint4 qb = *(const uint4*)(xb + ((unsigned)s1 << 7));
    uint4 qc = *(const uint4*)(xb + ((unsigned)s2 << 7));
    uint4 qd = *(const uint4*)(xb + ((unsigned)s3 << 7));
    const float w1 = (t + 1 < o1) ? 1.0f : 0.0f;
    const float w2 = (t + 2 < o1) ? 1.0f : 0.0f;
    const float w3 = (t + 3 < o1) ? 1.0f : 0.0f;
    int t4 = t + 4;
    s0 = (t4     < o1) ? csr[t4]     : 0;
    s1 = (t4 + 1 < o1) ? csr[t4 + 1] : 0;
    s2 = (t4 + 2 < o1) ? csr[t4 + 2] : 0;
    s3 = (t4 + 3 < o1) ? csr[t4 + 3] : 0;
    a0 += upk2(qa.x); a1 += upk2(qa.y); a2 += upk2(qa.z); a3 += upk2(qa.w);
    fma2(b0, qb.x, w1); fma2(b1, qb.y, w1); fma2(b2, qb.z, w1); fma2(b3, qb.w, w1);
    fma2(a0, qc.x, w2); fma2(a1, qc.y, w2); fma2(a2, qc.z, w2); fma2(a3, qc.w, w2);
    fma2(b0, qd.x, w3); fma2(b1, qd.y, w3); fma2(b2, qd.z, w3); fma2(b3, qd.w, w3);
    t = t4;
  }
  a0 += b0; a1 += b1; a2 += b2; a3 += b3;
  const float inv = __builtin_amdgcn_rcpf(fmaxf((float)(o1 - o0), 1.0f));
  uint4 q;
  q.x = cvtpk_bf16(a0.x * inv, a0.y * inv);
  q.y = cvtpk_bf16(a1.x * inv, a1.y * inv);
  q.z = cvtpk_bf16(a2.x * inv, a2.y * inv);
  q.w = cvtpk_bf16(a3.x * inv, a3.y * inv);
  *(uint4*)(row + fg * 16) = q;
}

// ---------------- CSR build -------------------------------------------------

__global__ __launch_bounds__(256)
void blockhist3_kernel(const int* __restrict__ d1, const int* __restrict__ d2,
                       const int* __restrict__ d3,
                       int* __restrict__ h1, int* __restrict__ h2, int* __restrict__ h3) {
  int which = blockIdx.x / PB;
  int blk = blockIdx.x % PB;
  const int* dp = (which == 0) ? d1 : (which == 1) ? d2 : d3;
  int* hp = (which == 0) ? h1 : (which == 1) ? h2 : h3;
  int nbc = (which == 0) ? NBC_PAT : NBC_STAY;
  __shared__ int lh[128];
  if (threadIdx.x < 128) lh[threadIdx.x] = 0;
  __syncthreads();
  int base = blk * 4096;
  int n = min(4096, N_EDGE - base);
  for (int i = threadIdx.x; i < n; i += 256)
    atomicAdd(&lh[dp[base + i] >> 11], 1);
  __syncthreads();
  if (threadIdx.x < nbc && lh[threadIdx.x])
    atomicAdd(&hp[threadIdx.x], lh[threadIdx.x]);
}

// single-block exclusive scan body, n <= 4096; writes off[0..n] and cur[0..n-1]
__device__ __forceinline__
void scan_dev(const int* __restrict__ in, int n, int* __restrict__ off,
              int* __restrict__ cur, int total) {
  int tid = threadIdx.x;
  int base = tid * 16;
  int vals[16]; int s = 0;
  #pragma unroll
  for (int i = 0; i < 16; ++i) {
    int idx = base + i;
    vals[i] = (idx < n) ? in[idx] : 0;
    s += vals[i];
  }
  int lane = tid & 63, w = tid >> 6;
  int incl = s;
  #pragma unroll
  for (int o = 1; o < 64; o <<= 1) {
    int t = __shfl_up(incl, o);
    if (lane >= o) incl += t;
  }
  __shared__ int wtot[4];
  if (lane == 63) wtot[w] = incl;
  __syncthreads();
  int wbase = 0;
  for (int i = 0; i < w; ++i) wbase += wtot[i];
  int run = wbase + incl - s;
  #pragma unroll
  for (int i = 0; i < 16; ++i) {
    int idx = base + i;
    if (idx < n) { off[idx] = run; cur[idx] = run; run += vals[i]; }
  }
  if (tid == 0) off[n] = total;
}

// three coarse-hist scans in one dispatch (block = which)
__global__ __launch_bounds__(256)
void scan3_kernel(const int* __restrict__ bh1, int* __restrict__ bo1, int* __restrict__ bc1,
                  const int* __restrict__ bh2, int* __restrict__ bo2, int* __restrict__ bc2,
                  const int* __restrict__ bh3, int* __restrict__ bo3, int* __restrict__ bc3) {
  if (blockIdx.x == 0)      scan_dev(bh1, NBC_PAT,  bo1, bc1, N_EDGE);
  else if (blockIdx.x == 1) scan_dev(bh2, NBC_STAY, bo2, bc2, N_EDGE);
  else                      scan_dev(bh3, NBC_STAY, bo3, bc3, N_EDGE);
}

// packed value = src | ((dst & 2047) << 18); bucket = dst >> 11
__global__ __launch_bounds__(256)
void phaseA3_kernel(const int* __restrict__ s1, const int* __restrict__ d1,
                    const int* __restrict__ s2, const int* __restrict__ d2,
                    const int* __restrict__ s3, const int* __restrict__ d3,
                    int* __restrict__ c1, int* __restrict__ c2, int* __restrict__ c3,
                    int* __restrict__ v1, int* __restrict__ v2, int* __restrict__ v3) {
  int which = blockIdx.x / PB;
  int blk = blockIdx.x % PB;
  const int* sp = (which == 0) ? s1 : (which == 1) ? s2 : s3;
  const int* dp = (which == 0) ? d1 : (which == 1) ? d2 : d3;
  int* cp = (which == 0) ? c1 : (which == 1) ? c2 : c3;
  int* vp = (which == 0) ? v1 : (which == 1) ? v2 : v3;
  int nbc = (which == 0) ? NBC_PAT : NBC_STAY;
  __shared__ int vals[4096];
  __shared__ unsigned char bkt[4096];
  __shared__ int lh[128], lbase[128], lcur[128], gbase[128];
  __shared__ int wt[2];
  const int tid = threadIdx.x;
  if (tid < 128) lh[tid] = 0;
  __syncthreads();
  int base = blk * 4096;
  int n = min(4096, N_EDGE - base);
  int pv[16], pbk[16];
  #pragma unroll
  for (int i = 0; i < 16; ++i) {
    int idx = i * 256 + tid;
    if (idx < n) {
      int e = base + idx;
      int d = dp[e], s = sp[e];
      pv[i] = s | ((d & 2047) << 18);
      pbk[i] = d >> 11;
      atomicAdd(&lh[pbk[i]], 1);
    } else pbk[i] = -1;
  }
  __syncthreads();
  // exclusive scan of lh[0..nbc) (nbc <= 98 < 128) via two waves
  {
    int lane = tid & 63, w = tid >> 6;
    int x = (tid < 128 && tid < nbc) ? lh[tid] : 0;
    int incl = x;
    #pragma unroll
    for (int o = 1; o < 64; o <<= 1) {
      int t = __shfl_up(incl, o);
      if (lane >= o) incl += t;
    }
    if (w < 2 && lane == 63) wt[w] = incl;
    __syncthreads();
    if (tid < 128) {
      int ex = incl - x + ((w == 1) ? wt[0] : 0);
      lbase[tid] = ex;
      lcur[tid] = ex;
    }
  }
  __syncthreads();
  // place into LDS sorted by bucket
  #pragma unroll
  for (int i = 0; i < 16; ++i) {
    if (pbk[i] >= 0) {
      int r = atomicAdd(&lcur[pbk[i]], 1);
      vals[r] = pv[i];
      bkt[r] = (unsigned char)pbk[i];
    }
  }
  __syncthreads();
  // reserve global space: one atomic per non-empty bucket group
  if (tid < nbc) {
    int cnt = lh[tid];
    gbase[tid] = cnt ? atomicAdd(&cp[tid], cnt) : 0;
  }
  __syncthreads();
  // contiguous run copy-out (consecutive i -> mostly consecutive addresses)
  for (int i = tid; i < n; i += 256) {
    int b = bkt[i];
    vp[gbase[b] + i - lbase[b]] = vals[i];
  }
}

// one block per coarse bucket: node-sorted csr + off[]
__global__ __launch_bounds__(256)
void phaseB3_kernel(const int* __restrict__ v1, const int* __restrict__ bo1,
                    const int* __restrict__ v2, const int* __restrict__ bo2,
                    const int* __restrict__ v3, const int* __restrict__ bo3,
                    int* __restrict__ csr1, int* __restrict__ off1,
                    int* __restrict__ csr2, int* __restrict__ off2,
                    int* __restrict__ csr3, int* __restrict__ off3) {
  int b = blockIdx.x;
  const int* v; const int* bo; int* csr; int* off; int N; int lb;
  if (b < NBC_PAT)                 { v = v1; bo = bo1; csr = csr1; off = off1; N = N_PAT;  lb = b; }
  else if (b < NBC_PAT + NBC_STAY) { v = v2; bo = bo2; csr = csr2; off = off2; N = N_STAY; lb = b - NBC_PAT; }
  else                             { v = v3; bo = bo3; csr = csr3; off = off3; N = N_STAY; lb = b - NBC_PAT - NBC_STAY; }
  const int tid = threadIdx.x;
  __shared__ int lh[2048];
  __shared__ int lcur[2048];
  __shared__ int wt[4];
  #pragma unroll
  for (int j = 0; j < 8; ++j) lh[tid + j * 256] = 0;
  __syncthreads();
  const int rb = bo[lb], re = bo[lb + 1];
  for (int i = rb + tid; i < re; i += 256)
    atomicAdd(&lh[(v[i] >> 18) & 2047], 1);
  __syncthreads();
  // block exclusive scan over 2048 -> lcur (+rb), emit off[]
  const int node_base = lb * 2048;
  const int b8 = tid * 8;
  int ex[8]; int run = 0;
  #pragma unroll
  for (int j = 0; j < 8; ++j) { ex[j] = run; run += lh[b8 + j]; }
  int lane = tid & 63, w = tid >> 6;
  int incl = run;
  #pragma unroll
  for (int o = 1; o < 64; o <<= 1) {
    int t = __shfl_up(incl, o);
    if (lane >= o) incl += t;
  }
  if (lane == 63) wt[w] = incl;
  __syncthreads();
  int wb = 0;
  for (int i = 0; i < w; ++i) wb += wt[i];
  const int tex = rb + wb + incl - run;
  #pragma unroll
  for (int j = 0; j < 8; ++j) {
    int pos = tex + ex[j];
    lcur[b8 + j] = pos;
    int node = node_base + b8 + j;
    if (node < N) off[node] = pos;
  }
  __syncthreads();
  for (int i = rb + tid; i < re; i += 256) {
    int val = v[i];
    int pos = atomicAdd(&lcur[(val >> 18) & 2047], 1);
    csr[pos] = val & 0x3FFFF;
  }
  if (b == 0 && tid == 0) {
    off1[N_PAT] = N_EDGE;
    off2[N_STAY] = N_EDGE;
    off3[N_STAY] = N_EDGE;
  }
}

// ---------------- weight preconversion to MFMA B-fragments (hi+lo bf16) -----

template<int K>
__device__ __forceinline__
void precvt_dev(const float* __restrict__ src, ushort_t* __restrict__ dst,
                int nmat, int blk) {
  const int KS = K / 32;
  const int FU = KS * 4;
  const int PLANE = FU * 64 * 8;
  int fu = blk * 4 + (threadIdx.x >> 6);
  int lane = threadIdx.x & 63;
  int mi = fu / FU;
  if (mi >= nmat) return;
  int fid = fu % FU;
  int ntile = fid / KS;
  int kstep = fid % KS;
  int q = lane >> 4, n = ntile * 16 + (lane & 15);
  const float* W = src + (size_t)mi * K * H;
  union { ushort_t s[8]; uint4 u; } hi, lo;
  #pragma unroll
  for (int j = 0; j < 8; ++j) {
    float v = W[(size_t)(kstep * 32 + q * 8 + j) * H + n];
    unsigned hb = f2bf_bits(v);
    hi.s[j] = (ushort_t)hb;
    lo.s[j] = (ushort_t)f2bf_bits(v - bf2f((ushort_t)hb));
  }
  ushort_t* base = dst + (size_t)mi * 2 * PLANE + ((size_t)fid * 64 + lane) * 8;
  *(uint4*)base = hi.u;
  *(uint4*)(base + PLANE) = lo.u;
}

// blocks [0,4)=WpS, [4,6)=WpP, [6,18)=Wl (6 mats), [18,30)=Wr (6 mats)
__global__ __launch_bounds__(256)
void precvt_all_kernel(const float* __restrict__ WpS, const float* __restrict__ WpP,
                       const float* __restrict__ Wl, const float* __restrict__ Wr,
                       ushort_t* __restrict__ fWpS, ushort_t* __restrict__ fWpP,
                       ushort_t* __restrict__ fWlB, ushort_t* __restrict__ fWrB) {
  int b = blockIdx.x;
  if (b < 4)        precvt_dev<128>(WpS, fWpS, 1, b);
  else if (b < 6)   precvt_dev<64>(WpP, fWpP, 1, b - 4);
  else if (b < 18)  precvt_dev<64>(Wl, fWlB, 6, b - 6);
  else              precvt_dev<64>(Wr, fWrB, 6, b - 18);
}

// ---------------- MFMA dense kernels ----------------------------------------

#define MFMA16(a, b, c) __builtin_amdgcn_mfma_f32_16x16x32_bf16((a), (b), (c), 0, 0, 0)

// proj with weight fragments staged in LDS; 512-thread blocks, 128 rows/block.
template<int K>
__device__ __forceinline__
void proj_lds_dev(const float* __restrict__ x, const ushort_t* __restrict__ fw,
                  const float* __restrict__ b, ushort_t* __restrict__ y,
                  int N, int blk, uint4* __restrict__ u4) {
  const int KS = K / 32;
  const int PLANE = KS * 4 * 64 * 8;       // ushorts per plane
  const int NU4 = PLANE / 4;               // uint4 count covering both planes
  const int tid = threadIdx.x;
  for (int i = tid; i < NU4; i += 512)
    u4[i] = ((const uint4*)fw)[i];
  __syncthreads();
  const ushort_t* w = (const ushort_t*)u4;
  const int wid = tid >> 6, lane = tid & 63;
  const int r0 = blk * 128 + wid * 16;
  if (r0 >= N) return;                     // after the barrier: safe
  const int m = lane & 15, q = lane >> 4;
  f32x4 c[4] = {{0,0,0,0},{0,0,0,0},{0,0,0,0},{0,0,0,0}};
  #pragma unroll
  for (int ks = 0; ks < KS; ++ks) {
    const float* xp = x + (size_t)(r0 + m) * K + ks * 32 + q * 8;
    float4 v0 = *(const float4*)xp;
    float4 v1 = *(const float4*)(xp + 4);
    float vv[8] = {v0.x, v0.y, v0.z, v0.w, v1.x, v1.y, v1.z, v1.w};
    union { ushort_t s[8]; bf16x8 v; } ah, al;
    #pragma unroll
    for (int j = 0; j < 8; ++j) {
      unsigned hb = f2bf_bits(vv[j]);
      ah.s[j] = (ushort_t)hb;
      al.s[j] = (ushort_t)f2bf_bits(vv[j] - bf2f((ushort_t)hb));
    }
    #pragma unroll
    for (int nt = 0; nt < 4; ++nt) {
      const ushort_t* fb = w + ((size_t)(nt * KS + ks) * 64 + lane) * 8;
      bf16x8 bh = ld_frag(fb);
      bf16x8 blo = ld_frag(fb + PLANE);
      c[nt] = MFMA16(ah.v, bh, c[nt]);
      c[nt] = MFMA16(ah.v, blo, c[nt]);
      c[nt] = MFMA16(al.v, bh, c[nt]);
    }
  }
  #pragma unroll
  for (int nt = 0; nt < 4; ++nt) {
    float bias = b[nt * 16 + m];
    #pragma unroll
    for (int r = 0; r < 4; ++r) {
      float o = fmaxf(c[nt][r] + bias, 0.0f);
      y[(size_t)(r0 + q * 4 + r) * H + nt * 16 + m] = (ushort_t)f2bf_bits(o);
    }
  }
}

// both projections in one dispatch: blocks [0,SB2_STAY)=stay K=128, rest pat K=64
__global__ __launch_bounds__(512)
void proj_both_kernel(const float* __restrict__ xs, const ushort_t* __restrict__ fws,
                      const float* __restrict__ bs,
                      const float* __restrict__ xp, const ushort_t* __restrict__ fwp,
                      const float* __restrict__ bp,
                      ushort_t* __restrict__ ys, ushort_t* __restrict__ yp) {
  __shared__ uint4 u4[2048];   // 32KB
  if (blockIdx.x < SB2_STAY) proj_lds_dev<128>(xs, fws, bs, ys, N_STAY, blockIdx.x, u4);
  else                       proj_lds_dev<64>(xp, fwp, bp, yp, N_PAT, blockIdx.x - SB2_STAY, u4);
}

// ---------------- FUSED agg + SAGE layer: stay + pat in ONE dispatch ---------
// Each wave gathers the neighbor-means of ITS OWN 16 nodes into a per-wave
// LDS slice (padded 144B rows), then consumes them as MFMA A-fragments.
// Removes the separate agg dispatches and the agg global round-trip.
// Inputs hin_* and outputs hout_* are PING-PONG buffers (no same-buffer
// write-while-gather race). HI-PLANE-ONLY weights read direct from L2
// (verified R8: absmax 0.0137 vs 0.0323). final!=0: regression head fused.
// LDS row layout: wave slice = wid*4608; type*2304 + ni*144 + fg*16.
// Fragment read at byte m*144 + q*16 + ks*64 (fg == ks*4+q).

__global__ __launch_bounds__(512)
void sage_fused_mfma(const ushort_t* __restrict__ hin_s, const ushort_t* __restrict__ hin_p,
                     const int* __restrict__ off1, const int* __restrict__ csr1,
                     const int* __restrict__ off2, const int* __restrict__ csr2,
                     const int* __restrict__ off3, const int* __restrict__ csr3,
                     const ushort_t* __restrict__ fWl0, const ushort_t* __restrict__ fWr0,
                     const ushort_t* __restrict__ fWl1, const ushort_t* __restrict__ fWr1,
                     const ushort_t* __restrict__ fWl2, const ushort_t* __restrict__ fWr2,
                     const float* __restrict__ bl0, const float* __restrict__ bl1,
                     const float* __restrict__ bl2,
                     const float* __restrict__ g, const float* __restrict__ bb,
                     ushort_t* __restrict__ hout_p, ushort_t* __restrict__ hout_s,
                     const float* __restrict__ Wreg, const float* __restrict__ breg,
                     float* __restrict__ reg_out, int final_l) {
  __shared__ __align__(16) char aggL[8 * 4608];   // 36,864 B
  const int tid = threadIdx.x;
  const int wid = tid >> 6, lane = tid & 63;
  const int m = lane & 15, q = lane >> 4;
  const int g8 = lane >> 3, fg = lane & 7;
  char* wsl = aggL + wid * 4608;

  if (blockIdx.x < SB2_STAY) {
    // ---------------- stay side ----------------
    const int r0 = blockIdx.x * 128 + wid * 16;   // wave window [r0, r0+16)
    // gather phase: 32 tasks (16 nodes x {agg2,agg3}) over 8 groups
    if (r0 < N_STAY) {   // windows never straddle (N_STAY % 16 == 0)
      #pragma unroll
      for (int t = 0; t < 4; ++t) {
        int task = g8 + t * 8;
        int type = task >> 4;      // 0: agg2 (pat->stay), 1: agg3 (stay->stay)
        int ni = task & 15;
        char* row = wsl + type * 2304 + ni * 144;
        if (type == 0) gather_row(hin_p, off2, csr2, r0 + ni, row, fg);
        else           gather_row(hin_s, off3, csr3, r0 + ni, row, fg);
      }
    }
    __syncthreads();
    if (r0 >= N_STAY) return;
    const ushort_t* a2r = (const ushort_t*)(wsl + m * 144);
    const ushort_t* a3r = (const ushort_t*)(wsl + 2304 + m * 144);
    const ushort_t* xp  = hin_s + (size_t)(r0 + m) * H + q * 8;
    bf16x8 A2[2], A3[2], X[2];
    A2[0] = ld_frag(a2r + q * 8);  A2[1] = ld_frag(a2r + q * 8 + 32);
    A3[0] = ld_frag(a3r + q * 8);  A3[1] = ld_frag(a3r + q * 8 + 32);
    X[0]  = ld_frag(xp);           X[1]  = ld_frag(xp + 32);
    f32x4 c2[4] = {{0,0,0,0},{0,0,0,0},{0,0,0,0},{0,0,0,0}};
    f32x4 c3[4] = {{0,0,0,0},{0,0,0,0},{0,0,0,0},{0,0,0,0}};
    #pragma unroll
    for (int nt = 0; nt < 4; ++nt) {
      #pragma unroll
      for (int ks = 0; ks < 2; ++ks) {
        const size_t fo = ((size_t)(nt * 2 + ks) * 64 + lane) * 8;
        bf16x8 bh = ld_frag(fWl1 + fo);
        c2[nt] = MFMA16(A2[ks], bh, c2[nt]);
        bh = ld_frag(fWr1 + fo);
        c2[nt] = MFMA16(X[ks], bh, c2[nt]);
        bh = ld_frag(fWl2 + fo);
        c3[nt] = MFMA16(A3[ks], bh, c3[nt]);
        bh = ld_frag(fWr2 + fo);
        c3[nt] = MFMA16(X[ks], bh, c3[nt]);
      }
    }
    float n2s[4] = {0,0,0,0}, n3s[4] = {0,0,0,0};
    #pragma unroll
    for (int nt = 0; nt < 4; ++nt) {
      float b2 = bl1[nt * 16 + m], b3 = bl2[nt * 16 + m];
      #pragma unroll
      for (int r = 0; r < 4; ++r) {
        c2[nt][r] += b2;
        c3[nt][r] += b3;
        n2s[r] = fmaf(c2[nt][r], c2[nt][r], n2s[r]);
        n3s[r] = fmaf(c3[nt][r], c3[nt][r], n3s[r]);
      }
    }
    #pragma unroll
    for (int off = 1; off < 16; off <<= 1)
      #pragma unroll
      for (int r = 0; r < 4; ++r) {
        n2s[r] += __shfl_xor(n2s[r], off);
        n3s[r] += __shfl_xor(n3s[r], off);
      }
    float r2v[4], r3v[4];
    #pragma unroll
    for (int r = 0; r < 4; ++r) {
      r2v[r] = 0.5f / fmaxf(sqrtf(n2s[r]), 1e-12f);
      r3v[r] = 0.5f / fmaxf(sqrtf(n3s[r]), 1e-12f);
    }
    float y[4][4];
    float s1[4] = {0,0,0,0}, s2[4] = {0,0,0,0};
    #pragma unroll
    for (int nt = 0; nt < 4; ++nt)
      #pragma unroll
      for (int r = 0; r < 4; ++r) {
        float v = fmaxf(fmaf(c2[nt][r], r2v[r], c3[nt][r] * r3v[r]), 0.0f);
        y[nt][r] = v;
        s1[r] += v;
        s2[r] = fmaf(v, v, s2[r]);
      }
    #pragma unroll
    for (int off = 1; off < 16; off <<= 1)
      #pragma unroll
      for (int r = 0; r < 4; ++r) {
        s1[r] += __shfl_xor(s1[r], off);
        s2[r] += __shfl_xor(s2[r], off);
      }
    float mean[4], sig[4];
    #pragma unroll
    for (int r = 0; r < 4; ++r) {
      mean[r] = s1[r] * (1.0f / H);
      float var = s2[r] * (1.0f / H) - mean[r] * mean[r];
      sig[r] = rsqrtf(var + 1e-5f);
    }
    unsigned int obits[4][4];
    #pragma unroll
    for (int nt = 0; nt < 4; ++nt) {
      float gv = g[nt * 16 + m], bv = bb[nt * 16 + m];
      #pragma unroll
      for (int r = 0; r < 4; ++r) {
        float o = (y[nt][r] - mean[r]) * sig[r] * gv + bv;
        obits[nt][r] = f2bf_bits(o);
        hout_s[(size_t)(r0 + q * 4 + r) * H + nt * 16 + m] = (ushort_t)obits[nt][r];
      }
    }
    if (final_l) {
      float wv[4];
      #pragma unroll
      for (int nt = 0; nt < 4; ++nt) wv[nt] = Wreg[nt * 16 + m];
      float p[4] = {0,0,0,0};
      #pragma unroll
      for (int nt = 0; nt < 4; ++nt)
        #pragma unroll
        for (int r = 0; r < 4; ++r)
          p[r] = fmaf(bf2f((ushort_t)obits[nt][r]), wv[nt], p[r]);
      #pragma unroll
      for (int off = 1; off < 16; off <<= 1)
        #pragma unroll
        for (int r = 0; r < 4; ++r) p[r] += __shfl_xor(p[r], off);
      if (m == 0) {
        float b0v = breg[0];
        #pragma unroll
        for (int r = 0; r < 4; ++r) reg_out[r0 + q * 4 + r] = p[r] + b0v;
      }
    }
  } else {
    // ---------------- pat side ----------------
    const int r0 = (blockIdx.x - SB2_STAY) * 128 + wid * 16;
    if (r0 < N_PAT) {   // windows never straddle (N_PAT % 16 == 0)
      #pragma unroll
      for (int t = 0; t < 2; ++t) {
        int ni = g8 + t * 8;   // 16 tasks: agg1 (stay->pat)
        gather_row(hin_s, off1, csr1, r0 + ni, wsl + ni * 144, fg);
      }
    }
    __syncthreads();
    if (r0 >= N_PAT) return;
    const ushort_t* ar = (const ushort_t*)(wsl + m * 144);
    const ushort_t* xp = hin_p + (size_t)(r0 + m) * H + q * 8;
    bf16x8 A[2], X[2];
    A[0] = ld_frag(ar + q * 8);  A[1] = ld_frag(ar + q * 8 + 32);
    X[0] = ld_frag(xp);          X[1] = ld_frag(xp + 32);
    f32x4 c[4] = {{0,0,0,0},{0,0,0,0},{0,0,0,0},{0,0,0,0}};
    #pragma unroll
    for (int nt = 0; nt < 4; ++nt) {
      #pragma unroll
      for (int ks = 0; ks < 2; ++ks) {
        const size_t fo = ((size_t)(nt * 2 + ks) * 64 + lane) * 8;
        bf16x8 bh = ld_frag(fWl0 + fo);
        c[nt] = MFMA16(A[ks], bh, c[nt]);
        bh = ld_frag(fWr0 + fo);
        c[nt] = MFMA16(X[ks], bh, c[nt]);
      }
    }
    float n2s[4] = {0, 0, 0, 0};
    #pragma unroll
    for (int nt = 0; nt < 4; ++nt) {
      float bias = bl0[nt * 16 + m];
      #pragma unroll
      for (int r = 0; r < 4; ++r) {
        c[nt][r] += bias;
        n2s[r] = fmaf(c[nt][r], c[nt][r], n2s[r]);
      }
    }
    #pragma unroll
    for (int off = 1; off < 16; off <<= 1)
      #pragma unroll
      for (int r = 0; r < 4; ++r) n2s[r] += __shfl_xor(n2s[r], off);
    float rv[4];
    #pragma unroll
    for (int r = 0; r < 4; ++r) rv[r] = 1.0f / fmaxf(sqrtf(n2s[r]), 1e-12f);
    float y[4][4];
    float s1[4] = {0,0,0,0}, s2[4] = {0,0,0,0};
    #pragma unroll
    for (int nt = 0; nt < 4; ++nt)
      #pragma unroll
      for (int r = 0; r < 4; ++r) {
        float v = fmaxf(c[nt][r] * rv[r], 0.0f);
        y[nt][r] = v;
        s1[r] += v;
        s2[r] = fmaf(v, v, s2[r]);
      }
    #pragma unroll
    for (int off = 1; off < 16; off <<= 1)
      #pragma unroll
      for (int r = 0; r < 4; ++r) {
        s1[r] += __shfl_xor(s1[r], off);
        s2[r] += __shfl_xor(s2[r], off);
      }
    float mean[4], sig[4];
    #pragma unroll
    for (int r = 0; r < 4; ++r) {
      mean[r] = s1[r] * (1.0f / H);
      float var = s2[r] * (1.0f / H) - mean[r] * mean[r];
      sig[r] = rsqrtf(var + 1e-5f);
    }
    #pragma unroll
    for (int nt = 0; nt < 4; ++nt) {
      float gv = g[nt * 16 + m], bv = bb[nt * 16 + m];
      #pragma unroll
      for (int r = 0; r < 4; ++r) {
        float o = (y[nt][r] - mean[r]) * sig[r] * gv + bv;
        hout_p[(size_t)(r0 + q * 4 + r) * H + nt * 16 + m] = (ushort_t)f2bf_bits(o);
      }
    }
  }
}

// -----------------------------------------------------------------------------

extern "C" void kernel_launch(void* const* d_in, const int* in_sizes, int n_in,
                              void* d_out, int out_size, void* d_ws, size_t ws_size,
                              hipStream_t stream) {
  const float* x_stay  = (const float*)d_in[0];
  const float* x_pat   = (const float*)d_in[1];
  const float* Wp_stay = (const float*)d_in[2];
  const float* bp_stay = (const float*)d_in[3];
  const float* Wp_pat  = (const float*)d_in[4];
  const float* bp_pat  = (const float*)d_in[5];
  const float* Wl      = (const float*)d_in[6];
  const float* bl      = (const float*)d_in[7];
  const float* Wr      = (const float*)d_in[8];
  const float* ln_g    = (const float*)d_in[9];
  const float* ln_b    = (const float*)d_in[10];
  const float* Wreg    = (const float*)d_in[11];
  const float* breg    = (const float*)d_in[12];
  const int* e1s = (const int*)d_in[13];
  const int* e1d = (const int*)d_in[14];
  const int* e2s = (const int*)d_in[15];
  const int* e2d = (const int*)d_in[16];
  const int* e3s = (const int*)d_in[17];
  const int* e3d = (const int*)d_in[18];
  float* out = (float*)d_out;

  const size_t S = (size_t)N_STAY * H;
  const size_t P = (size_t)N_PAT * H;

  // ping-pong hidden buffers (layer0: h0->h1, layer1: h1->h0)
  ushort_t* hs0  = (ushort_t*)d_ws;
  ushort_t* hp0  = hs0 + S;
  ushort_t* hs1  = hp0 + P;
  ushort_t* hp1  = hs1 + S;
  ushort_t* fragW = hp1 + P;
  ushort_t* fWpS = fragW;                // K=128: 2*8192
  ushort_t* fWpP = fragW + 16384;        // K=64:  2*4096
  ushort_t* fWlB = fragW + 24576;        // 6 * 8192
  ushort_t* fWrB = fragW + 24576 + 49152;
  int* ib    = (int*)(fragW + 122880);
  int* off1  = ib;                         // N_PAT+1
  int* off2  = off1 + (N_PAT + 1);         // N_STAY+1
  int* off3  = off2 + (N_STAY + 1);        // N_STAY+1
  int* bh1   = off3 + (N_STAY + 1);        // coarse hists, contiguous
  int* bh2   = bh1 + NBC_PAT;
  int* bh3   = bh2 + NBC_STAY;
  int* bo1   = bh3 + NBC_STAY;             // NBC_PAT+1
  int* bo2   = bo1 + (NBC_PAT + 1);        // NBC_STAY+1
  int* bo3   = bo2 + (NBC_STAY + 1);       // NBC_STAY+1
  int* bc1   = bo3 + (NBC_STAY + 1);       // cursors
  int* bc2   = bc1 + NBC_PAT;
  int* bc3   = bc2 + NBC_STAY;
  int* bv1   = bc3 + NBC_STAY;             // binned packed values, E each
  int* bv2   = bv1 + N_EDGE;
  int* bv3   = bv2 + N_EDGE;
  int* csr1  = bv3 + N_EDGE;               // E each
  int* csr2  = csr1 + N_EDGE;
  int* csr3  = csr2 + N_EDGE;

  // weight preconversion (tiny, one dispatch)
  precvt_all_kernel<<<30, 256, 0, stream>>>(Wp_stay, Wp_pat, Wl, Wr,
                                            fWpS, fWpP, fWlB, fWrB);

  // CSR build (R3-proven structure)
  hipMemsetAsync(bh1, 0, (size_t)(NBC_PAT + 2 * NBC_STAY) * sizeof(int), stream);
  blockhist3_kernel<<<3 * PB, 256, 0, stream>>>(e1d, e2d, e3d, bh1, bh2, bh3);
  scan3_kernel<<<3, 256, 0, stream>>>(bh1, bo1, bc1, bh2, bo2, bc2, bh3, bo3, bc3);
  phaseA3_kernel<<<3 * PB, 256, 0, stream>>>(e1s, e1d, e2s, e2d, e3s, e3d,
                                             bc1, bc2, bc3, bv1, bv2, bv3);
  phaseB3_kernel<<<NBC_PAT + 2 * NBC_STAY, 256, 0, stream>>>(
      bv1, bo1, bv2, bo2, bv3, bo3, csr1, off1, csr2, off2, csr3, off3);

  // input projections (LDS-staged weights, 512-thread blocks)
  proj_both_kernel<<<SB2_STAY + SB2_PAT, 512, 0, stream>>>(
      x_stay, fWpS, bp_stay, x_pat, fWpP, bp_pat, hs0, hp0);

  for (int l = 0; l < 2; ++l) {
    ushort_t* fWl0 = fWlB + (size_t)(l * 3 + 0) * 8192;
    ushort_t* fWl1 = fWlB + (size_t)(l * 3 + 1) * 8192;
    ushort_t* fWl2 = fWlB + (size_t)(l * 3 + 2) * 8192;
    ushort_t* fWr0 = fWrB + (size_t)(l * 3 + 0) * 8192;
    ushort_t* fWr1 = fWrB + (size_t)(l * 3 + 1) * 8192;
    ushort_t* fWr2 = fWrB + (size_t)(l * 3 + 2) * 8192;
    const float* bl0 = bl + (size_t)(l * 3 + 0) * H;
    const float* bl1 = bl + (size_t)(l * 3 + 1) * H;
    const float* bl2 = bl + (size_t)(l * 3 + 2) * H;
    const float* g  = ln_g + (size_t)l * H;
    const float* bb = ln_b + (size_t)l * H;

    const ushort_t* hin_s = (l == 0) ? hs0 : hs1;
    const ushort_t* hin_p = (l == 0) ? hp0 : hp1;
    ushort_t* hout_s = (l == 0) ? hs1 : hs0;
    ushort_t* hout_p = (l == 0) ? hp1 : hp0;

    sage_fused_mfma<<<SB2_STAY + SB2_PAT, 512, 0, stream>>>(
        hin_s, hin_p, off1, csr1, off2, csr2, off3, csr3,
        fWl0, fWr0, fWl1, fWr1, fWl2, fWr2,
        bl0, bl1, bl2, g, bb,
        hout_p, hout_s, Wreg, breg, out, (l == 1) ? 1 : 0);
  }
}

// Round 11
// 465.893 us; speedup vs baseline: 1.0674x; 1.0067x over previous
//
#include <hip/hip_runtime.h>

#define H 64
#define N_STAY 200000
#define N_PAT  100000
#define N_EDGE 1000000
#define NBC_STAY 98    // ceil(200000/2048)
#define NBC_PAT  49    // ceil(100000/2048)
#define PB 245         // ceil(1e6/4096) edge blocks of 4096

#define SB2_STAY 1563  // ceil(200000/128) 512-thread blocks
#define SB2_PAT  782   // ceil(100000/128)

typedef unsigned short ushort_t;
typedef __attribute__((ext_vector_type(8))) short bf16x8;
typedef __attribute__((ext_vector_type(4))) float f32x4;
typedef __attribute__((ext_vector_type(2))) float f32x2;

__device__ __forceinline__ float bf2f(ushort_t u) {
  union { unsigned int i; float f; } c;
  c.i = ((unsigned int)u) << 16;
  return c.f;
}
__device__ __forceinline__ unsigned int f2bf_bits(float f) {
  union { float v; unsigned int i; } c; c.v = f;
  unsigned int r = c.i + 0x7fffu + ((c.i >> 16) & 1u);  // RNE
  return r >> 16;
}
__device__ __forceinline__ bf16x8 ld_frag(const ushort_t* p) {
  union { uint4 u; bf16x8 v; } c;
  c.u = *(const uint4*)p;
  return c.v;
}

// ---- agg helpers -----------------------------------------------------------

__device__ __forceinline__ f32x2 upk2(unsigned int u) {
  f32x2 r;
  r.x = __uint_as_float(u << 16);
  r.y = __uint_as_float(u & 0xffff0000u);
  return r;
}
__device__ __forceinline__ void fma2(f32x2& a, unsigned int u, float w) {
  a.x = fmaf(__uint_as_float(u << 16), w, a.x);
  a.y = fmaf(__uint_as_float(u & 0xffff0000u), w, a.y);
}
__device__ __forceinline__ unsigned int cvtpk_bf16(float lo, float hi) {
  unsigned int r;
  asm("v_cvt_pk_bf16_f32 %0, %1, %2" : "=v"(r) : "v"(lo), "v"(hi));
  return r;
}

// gather mean of neighbor rows into one 128B LDS row (8 lanes cooperate,
// lane covers bytes [fg*16, fg*16+16)). Identical math to the old agg kernel
// (4-deep unroll, masked fma tail, rcp mean, cvt_pk pack) -> bitwise-same agg.
__device__ __forceinline__
void gather_row(const ushort_t* __restrict__ x, const int* __restrict__ off,
                const int* __restrict__ csr, int node,
                char* __restrict__ row, int fg) {
  const int o0 = off[node], o1 = off[node + 1];
  const char* xb = (const char*)x + (fg << 4);
  f32x2 a0 = {0.f,0.f}, a1 = {0.f,0.f}, a2 = {0.f,0.f}, a3 = {0.f,0.f};
  f32x2 b0 = {0.f,0.f}, b1 = {0.f,0.f}, b2 = {0.f,0.f}, b3 = {0.f,0.f};
  int t = o0;
  int s0 = (t     < o1) ? csr[t]     : 0;
  int s1 = (t + 1 < o1) ? csr[t + 1] : 0;
  int s2 = (t + 2 < o1) ? csr[t + 2] : 0;
  int s3 = (t + 3 < o1) ? csr[t + 3] : 0;
  while (t < o1) {
    uint4 qa = *(const uint4*)(xb + ((unsigned)s0 << 7));
    uint4 qb = *(const uint4*)(xb + ((unsigned)s1 << 7));
    uint4 qc = *(const uint4*)(xb + ((unsigned)s2 << 7));
    uint4 qd = *(const uint4*)(xb + ((unsigned)s3 << 7));
    const float w1 = (t + 1 < o1) ? 1.0f : 0.0f;
    const float w2 = (t + 2 < o1) ? 1.0f : 0.0f;
    const float w3 = (t + 3 < o1) ? 1.0f : 0.0f;
    int t4 = t + 4;
    s0 = (t4     < o1) ? csr[t4]     : 0;
    s1 = (t4 + 1 < o1) ? csr[t4 + 1] : 0;
    s2 = (t4 + 2 < o1) ? csr[t4 + 2] : 0;
    s3 = (t4 + 3 < o1) ? csr[t4 + 3] : 0;
    a0 += upk2(qa.x); a1 += upk2(qa.y); a2 += upk2(qa.z); a3 += upk2(qa.w);
    fma2(b0, qb.x, w1); fma2(b1, qb.y, w1); fma2(b2, qb.z, w1); fma2(b3, qb.w, w1);
    fma2(a0, qc.x, w2); fma2(a1, qc.y, w2); fma2(a2, qc.z, w2); fma2(a3, qc.w, w2);
    fma2(b0, qd.x, w3); fma2(b1, qd.y, w3); fma2(b2, qd.z, w3); fma2(b3, qd.w, w3);
    t = t4;
  }
  a0 += b0; a1 += b1; a2 += b2; a3 += b3;
  const float inv = __builtin_amdgcn_rcpf(fmaxf((float)(o1 - o0), 1.0f));
  uint4 q;
  q.x = cvtpk_bf16(a0.x * inv, a0.y * inv);
  q.y = cvtpk_bf16(a1.x * inv, a1.y * inv);
  q.z = cvtpk_bf16(a2.x * inv, a2.y * inv);
  q.w = cvtpk_bf16(a3.x * inv, a3.y * inv);
  *(uint4*)(row + fg * 16) = q;
}

// ---------------- CSR build -------------------------------------------------

__global__ __launch_bounds__(256)
void blockhist3_kernel(const int* __restrict__ d1, const int* __restrict__ d2,
                       const int* __restrict__ d3,
                       int* __restrict__ h1, int* __restrict__ h2, int* __restrict__ h3) {
  int which = blockIdx.x / PB;
  int blk = blockIdx.x % PB;
  const int* dp = (which == 0) ? d1 : (which == 1) ? d2 : d3;
  int* hp = (which == 0) ? h1 : (which == 1) ? h2 : h3;
  int nbc = (which == 0) ? NBC_PAT : NBC_STAY;
  __shared__ int lh[128];
  if (threadIdx.x < 128) lh[threadIdx.x] = 0;
  __syncthreads();
  int base = blk * 4096;
  int n = min(4096, N_EDGE - base);
  for (int i = threadIdx.x; i < n; i += 256)
    atomicAdd(&lh[dp[base + i] >> 11], 1);
  __syncthreads();
  if (threadIdx.x < nbc && lh[threadIdx.x])
    atomicAdd(&hp[threadIdx.x], lh[threadIdx.x]);
}

// single-block exclusive scan body, n <= 4096; writes off[0..n] and cur[0..n-1]
__device__ __forceinline__
void scan_dev(const int* __restrict__ in, int n, int* __restrict__ off,
              int* __restrict__ cur, int total) {
  int tid = threadIdx.x;
  int base = tid * 16;
  int vals[16]; int s = 0;
  #pragma unroll
  for (int i = 0; i < 16; ++i) {
    int idx = base + i;
    vals[i] = (idx < n) ? in[idx] : 0;
    s += vals[i];
  }
  int lane = tid & 63, w = tid >> 6;
  int incl = s;
  #pragma unroll
  for (int o = 1; o < 64; o <<= 1) {
    int t = __shfl_up(incl, o);
    if (lane >= o) incl += t;
  }
  __shared__ int wtot[4];
  if (lane == 63) wtot[w] = incl;
  __syncthreads();
  int wbase = 0;
  for (int i = 0; i < w; ++i) wbase += wtot[i];
  int run = wbase + incl - s;
  #pragma unroll
  for (int i = 0; i < 16; ++i) {
    int idx = base + i;
    if (idx < n) { off[idx] = run; cur[idx] = run; run += vals[i]; }
  }
  if (tid == 0) off[n] = total;
}

// three coarse-hist scans in one dispatch (block = which)
__global__ __launch_bounds__(256)
void scan3_kernel(const int* __restrict__ bh1, int* __restrict__ bo1, int* __restrict__ bc1,
                  const int* __restrict__ bh2, int* __restrict__ bo2, int* __restrict__ bc2,
                  const int* __restrict__ bh3, int* __restrict__ bo3, int* __restrict__ bc3) {
  if (blockIdx.x == 0)      scan_dev(bh1, NBC_PAT,  bo1, bc1, N_EDGE);
  else if (blockIdx.x == 1) scan_dev(bh2, NBC_STAY, bo2, bc2, N_EDGE);
  else                      scan_dev(bh3, NBC_STAY, bo3, bc3, N_EDGE);
}

// packed value = src | ((dst & 2047) << 18); bucket = dst >> 11
__global__ __launch_bounds__(256)
void phaseA3_kernel(const int* __restrict__ s1, const int* __restrict__ d1,
                    const int* __restrict__ s2, const int* __restrict__ d2,
                    const int* __restrict__ s3, const int* __restrict__ d3,
                    int* __restrict__ c1, int* __restrict__ c2, int* __restrict__ c3,
                    int* __restrict__ v1, int* __restrict__ v2, int* __restrict__ v3) {
  int which = blockIdx.x / PB;
  int blk = blockIdx.x % PB;
  const int* sp = (which == 0) ? s1 : (which == 1) ? s2 : s3;
  const int* dp = (which == 0) ? d1 : (which == 1) ? d2 : d3;
  int* cp = (which == 0) ? c1 : (which == 1) ? c2 : c3;
  int* vp = (which == 0) ? v1 : (which == 1) ? v2 : v3;
  int nbc = (which == 0) ? NBC_PAT : NBC_STAY;
  __shared__ int vals[4096];
  __shared__ unsigned char bkt[4096];
  __shared__ int lh[128], lbase[128], lcur[128], gbase[128];
  __shared__ int wt[2];
  const int tid = threadIdx.x;
  if (tid < 128) lh[tid] = 0;
  __syncthreads();
  int base = blk * 4096;
  int n = min(4096, N_EDGE - base);
  int pv[16], pbk[16];
  #pragma unroll
  for (int i = 0; i < 16; ++i) {
    int idx = i * 256 + tid;
    if (idx < n) {
      int e = base + idx;
      int d = dp[e], s = sp[e];
      pv[i] = s | ((d & 2047) << 18);
      pbk[i] = d >> 11;
      atomicAdd(&lh[pbk[i]], 1);
    } else pbk[i] = -1;
  }
  __syncthreads();
  // exclusive scan of lh[0..nbc) (nbc <= 98 < 128) via two waves
  {
    int lane = tid & 63, w = tid >> 6;
    int x = (tid < 128 && tid < nbc) ? lh[tid] : 0;
    int incl = x;
    #pragma unroll
    for (int o = 1; o < 64; o <<= 1) {
      int t = __shfl_up(incl, o);
      if (lane >= o) incl += t;
    }
    if (w < 2 && lane == 63) wt[w] = incl;
    __syncthreads();
    if (tid < 128) {
      int ex = incl - x + ((w == 1) ? wt[0] : 0);
      lbase[tid] = ex;
      lcur[tid] = ex;
    }
  }
  __syncthreads();
  // place into LDS sorted by bucket
  #pragma unroll
  for (int i = 0; i < 16; ++i) {
    if (pbk[i] >= 0) {
      int r = atomicAdd(&lcur[pbk[i]], 1);
      vals[r] = pv[i];
      bkt[r] = (unsigned char)pbk[i];
    }
  }
  __syncthreads();
  // reserve global space: one atomic per non-empty bucket group
  if (tid < nbc) {
    int cnt = lh[tid];
    gbase[tid] = cnt ? atomicAdd(&cp[tid], cnt) : 0;
  }
  __syncthreads();
  // contiguous run copy-out (consecutive i -> mostly consecutive addresses)
  for (int i = tid; i < n; i += 256) {
    int b = bkt[i];
    vp[gbase[b] + i - lbase[b]] = vals[i];
  }
}

// one block per coarse bucket: node-sorted csr + off[]
__global__ __launch_bounds__(256)
void phaseB3_kernel(const int* __restrict__ v1, const int* __restrict__ bo1,
                    const int* __restrict__ v2, const int* __restrict__ bo2,
                    const int* __restrict__ v3, const int* __restrict__ bo3,
                    int* __restrict__ csr1, int* __restrict__ off1,
                    int* __restrict__ csr2, int* __restrict__ off2,
                    int* __restrict__ csr3, int* __restrict__ off3) {
  int b = blockIdx.x;
  const int* v; const int* bo; int* csr; int* off; int N; int lb;
  if (b < NBC_PAT)                 { v = v1; bo = bo1; csr = csr1; off = off1; N = N_PAT;  lb = b; }
  else if (b < NBC_PAT + NBC_STAY) { v = v2; bo = bo2; csr = csr2; off = off2; N = N_STAY; lb = b - NBC_PAT; }
  else                             { v = v3; bo = bo3; csr = csr3; off = off3; N = N_STAY; lb = b - NBC_PAT - NBC_STAY; }
  const int tid = threadIdx.x;
  __shared__ int lh[2048];
  __shared__ int lcur[2048];
  __shared__ int wt[4];
  #pragma unroll
  for (int j = 0; j < 8; ++j) lh[tid + j * 256] = 0;
  __syncthreads();
  const int rb = bo[lb], re = bo[lb + 1];
  for (int i = rb + tid; i < re; i += 256)
    atomicAdd(&lh[(v[i] >> 18) & 2047], 1);
  __syncthreads();
  // block exclusive scan over 2048 -> lcur (+rb), emit off[]
  const int node_base = lb * 2048;
  const int b8 = tid * 8;
  int ex[8]; int run = 0;
  #pragma unroll
  for (int j = 0; j < 8; ++j) { ex[j] = run; run += lh[b8 + j]; }
  int lane = tid & 63, w = tid >> 6;
  int incl = run;
  #pragma unroll
  for (int o = 1; o < 64; o <<= 1) {
    int t = __shfl_up(incl, o);
    if (lane >= o) incl += t;
  }
  if (lane == 63) wt[w] = incl;
  __syncthreads();
  int wb = 0;
  for (int i = 0; i < w; ++i) wb += wt[i];
  const int tex = rb + wb + incl - run;
  #pragma unroll
  for (int j = 0; j < 8; ++j) {
    int pos = tex + ex[j];
    lcur[b8 + j] = pos;
    int node = node_base + b8 + j;
    if (node < N) off[node] = pos;
  }
  __syncthreads();
  for (int i = rb + tid; i < re; i += 256) {
    int val = v[i];
    int pos = atomicAdd(&lcur[(val >> 18) & 2047], 1);
    csr[pos] = val & 0x3FFFF;
  }
  if (b == 0 && tid == 0) {
    off1[N_PAT] = N_EDGE;
    off2[N_STAY] = N_EDGE;
    off3[N_STAY] = N_EDGE;
  }
}

// ---------------- weight preconversion to MFMA B-fragments (hi+lo bf16) -----

template<int K>
__device__ __forceinline__
void precvt_dev(const float* __restrict__ src, ushort_t* __restrict__ dst,
                int nmat, int blk) {
  const int KS = K / 32;
  const int FU = KS * 4;
  const int PLANE = FU * 64 * 8;
  int fu = blk * 4 + (threadIdx.x >> 6);
  int lane = threadIdx.x & 63;
  int mi = fu / FU;
  if (mi >= nmat) return;
  int fid = fu % FU;
  int ntile = fid / KS;
  int kstep = fid % KS;
  int q = lane >> 4, n = ntile * 16 + (lane & 15);
  const float* W = src + (size_t)mi * K * H;
  union { ushort_t s[8]; uint4 u; } hi, lo;
  #pragma unroll
  for (int j = 0; j < 8; ++j) {
    float v = W[(size_t)(kstep * 32 + q * 8 + j) * H + n];
    unsigned hb = f2bf_bits(v);
    hi.s[j] = (ushort_t)hb;
    lo.s[j] = (ushort_t)f2bf_bits(v - bf2f((ushort_t)hb));
  }
  ushort_t* base = dst + (size_t)mi * 2 * PLANE + ((size_t)fid * 64 + lane) * 8;
  *(uint4*)base = hi.u;
  *(uint4*)(base + PLANE) = lo.u;
}

// blocks [0,4)=WpS, [4,6)=WpP, [6,18)=Wl (6 mats), [18,30)=Wr (6 mats)
__global__ __launch_bounds__(256)
void precvt_all_kernel(const float* __restrict__ WpS, const float* __restrict__ WpP,
                       const float* __restrict__ Wl, const float* __restrict__ Wr,
                       ushort_t* __restrict__ fWpS, ushort_t* __restrict__ fWpP,
                       ushort_t* __restrict__ fWlB, ushort_t* __restrict__ fWrB) {
  int b = blockIdx.x;
  if (b < 4)        precvt_dev<128>(WpS, fWpS, 1, b);
  else if (b < 6)   precvt_dev<64>(WpP, fWpP, 1, b - 4);
  else if (b < 18)  precvt_dev<64>(Wl, fWlB, 6, b - 6);
  else              precvt_dev<64>(Wr, fWrB, 6, b - 18);
}

// ---------------- MFMA dense kernels ----------------------------------------

#define MFMA16(a, b, c) __builtin_amdgcn_mfma_f32_16x16x32_bf16((a), (b), (c), 0, 0, 0)

// proj, R11: x loads COALESCED via per-wave LDS transpose staging.
// Old pattern: lane (q,m) loaded 16B at (r0+m)*K -> 64-way 16B scatter per
// instruction (~64 L2 transactions each) -> transaction-rate bound (explains
// R6/R9 nulls: neither occupancy nor MLP changed request count).
// New: lane (lr=lane>>2, lc=lane&3) loads [r0+lr][ks*32+lc*4(+16)] -> each
// instruction touches 16 contiguous 64B line-aligned segments. Lanes stage
// the 16x32 f32 chunk in a per-wave LDS slice (36-dword row stride = b128
// bank floor), then read MFMA fragments from LDS (2-way, free). Wave-private
// slice -> no barriers in the loop; next chunk prefetched in registers.
template<int K>
__device__ __forceinline__
void proj_lds_dev(const float* __restrict__ x, const ushort_t* __restrict__ fw,
                  const float* __restrict__ b, ushort_t* __restrict__ y,
                  int N, int blk, uint4* __restrict__ u4, float* __restrict__ xs) {
  const int KS = K / 32;
  const int PLANE = KS * 4 * 64 * 8;       // ushorts per plane
  const int NU4 = PLANE / 4;               // uint4 count covering both planes
  const int tid = threadIdx.x;
  for (int i = tid; i < NU4; i += 512)
    u4[i] = ((const uint4*)fw)[i];
  __syncthreads();
  const ushort_t* w = (const ushort_t*)u4;
  const int wid = tid >> 6, lane = tid & 63;
  const int r0 = blk * 128 + wid * 16;
  if (r0 >= N) return;                     // after the barrier: safe
  const int m = lane & 15, q = lane >> 4;
  const int lr = lane >> 2, lc = lane & 3;
  float* sl = xs + wid * 576;              // 16 rows x 36 dwords per wave
  const float* xrow = x + (size_t)(r0 + lr) * K + lc * 4;
  float* wr0 = sl + lr * 36 + lc * 4;
  float* wr1 = wr0 + 16;
  const float* rd = sl + m * 36 + q * 8;
  f32x4 c[4] = {{0,0,0,0},{0,0,0,0},{0,0,0,0},{0,0,0,0}};
  float4 va = *(const float4*)xrow;
  float4 vb = *(const float4*)(xrow + 16);
  #pragma unroll
  for (int ks = 0; ks < KS; ++ks) {
    *(float4*)wr0 = va;
    *(float4*)wr1 = vb;
    if (ks + 1 < KS) {
      va = *(const float4*)(xrow + (ks + 1) * 32);
      vb = *(const float4*)(xrow + (ks + 1) * 32 + 16);
    }
    float4 v0 = *(const float4*)rd;
    float4 v1 = *(const float4*)(rd + 4);
    float vv[8] = {v0.x, v0.y, v0.z, v0.w, v1.x, v1.y, v1.z, v1.w};
    union { ushort_t s[8]; bf16x8 v; } ah, al;
    #pragma unroll
    for (int j = 0; j < 8; ++j) {
      unsigned hb = f2bf_bits(vv[j]);
      ah.s[j] = (ushort_t)hb;
      al.s[j] = (ushort_t)f2bf_bits(vv[j] - bf2f((ushort_t)hb));
    }
    #pragma unroll
    for (int nt = 0; nt < 4; ++nt) {
      const ushort_t* fb = w + ((size_t)(nt * KS + ks) * 64 + lane) * 8;
      bf16x8 bh = ld_frag(fb);
      bf16x8 blo = ld_frag(fb + PLANE);
      c[nt] = MFMA16(ah.v, bh, c[nt]);
      c[nt] = MFMA16(ah.v, blo, c[nt]);
      c[nt] = MFMA16(al.v, bh, c[nt]);
    }
  }
  #pragma unroll
  for (int nt = 0; nt < 4; ++nt) {
    float bias = b[nt * 16 + m];
    #pragma unroll
    for (int r = 0; r < 4; ++r) {
      float o = fmaxf(c[nt][r] + bias, 0.0f);
      y[(size_t)(r0 + q * 4 + r) * H + nt * 16 + m] = (ushort_t)f2bf_bits(o);
    }
  }
}

// both projections in one dispatch: blocks [0,SB2_STAY)=stay K=128, rest pat K=64
__global__ __launch_bounds__(512)
void proj_both_kernel(const float* __restrict__ xs_in, const ushort_t* __restrict__ fws,
                      const float* __restrict__ bs,
                      const float* __restrict__ xp_in, const ushort_t* __restrict__ fwp,
                      const float* __restrict__ bp,
                      ushort_t* __restrict__ ys, ushort_t* __restrict__ yp) {
  __shared__ uint4 u4[2048];      // 32KB weights
  __shared__ float xtile[4608];   // 18KB: 8 waves x 16 rows x 36 dwords
  if (blockIdx.x < SB2_STAY)
    proj_lds_dev<128>(xs_in, fws, bs, ys, N_STAY, blockIdx.x, u4, xtile);
  else
    proj_lds_dev<64>(xp_in, fwp, bp, yp, N_PAT, blockIdx.x - SB2_STAY, u4, xtile);
}

// ---------------- FUSED agg + SAGE layer: stay + pat in ONE dispatch ---------
// (unchanged from R10 — verified 469us, absmax 0.01367, replay clean)

__global__ __launch_bounds__(512)
void sage_fused_mfma(const ushort_t* __restrict__ hin_s, const ushort_t* __restrict__ hin_p,
                     const int* __restrict__ off1, const int* __restrict__ csr1,
                     const int* __restrict__ off2, const int* __restrict__ csr2,
                     const int* __restrict__ off3, const int* __restrict__ csr3,
                     const ushort_t* __restrict__ fWl0, const ushort_t* __restrict__ fWr0,
                     const ushort_t* __restrict__ fWl1, const ushort_t* __restrict__ fWr1,
                     const ushort_t* __restrict__ fWl2, const ushort_t* __restrict__ fWr2,
                     const float* __restrict__ bl0, const float* __restrict__ bl1,
                     const float* __restrict__ bl2,
                     const float* __restrict__ g, const float* __restrict__ bb,
                     ushort_t* __restrict__ hout_p, ushort_t* __restrict__ hout_s,
                     const float* __restrict__ Wreg, const float* __restrict__ breg,
                     float* __restrict__ reg_out, int final_l) {
  __shared__ __align__(16) char aggL[8 * 4608];   // 36,864 B
  const int tid = threadIdx.x;
  const int wid = tid >> 6, lane = tid & 63;
  const int m = lane & 15, q = lane >> 4;
  const int g8 = lane >> 3, fg = lane & 7;
  char* wsl = aggL + wid * 4608;

  if (blockIdx.x < SB2_STAY) {
    // ---------------- stay side ----------------
    const int r0 = blockIdx.x * 128 + wid * 16;   // wave window [r0, r0+16)
    if (r0 < N_STAY) {   // windows never straddle (N_STAY % 16 == 0)
      #pragma unroll
      for (int t = 0; t < 4; ++t) {
        int task = g8 + t * 8;
        int type = task >> 4;      // 0: agg2 (pat->stay), 1: agg3 (stay->stay)
        int ni = task & 15;
        char* row = wsl + type * 2304 + ni * 144;
        if (type == 0) gather_row(hin_p, off2, csr2, r0 + ni, row, fg);
        else           gather_row(hin_s, off3, csr3, r0 + ni, row, fg);
      }
    }
    __syncthreads();
    if (r0 >= N_STAY) return;
    const ushort_t* a2r = (const ushort_t*)(wsl + m * 144);
    const ushort_t* a3r = (const ushort_t*)(wsl + 2304 + m * 144);
    const ushort_t* xp  = hin_s + (size_t)(r0 + m) * H + q * 8;
    bf16x8 A2[2], A3[2], X[2];
    A2[0] = ld_frag(a2r + q * 8);  A2[1] = ld_frag(a2r + q * 8 + 32);
    A3[0] = ld_frag(a3r + q * 8);  A3[1] = ld_frag(a3r + q * 8 + 32);
    X[0]  = ld_frag(xp);           X[1]  = ld_frag(xp + 32);
    f32x4 c2[4] = {{0,0,0,0},{0,0,0,0},{0,0,0,0},{0,0,0,0}};
    f32x4 c3[4] = {{0,0,0,0},{0,0,0,0},{0,0,0,0},{0,0,0,0}};
    #pragma unroll
    for (int nt = 0; nt < 4; ++nt) {
      #pragma unroll
      for (int ks = 0; ks < 2; ++ks) {
        const size_t fo = ((size_t)(nt * 2 + ks) * 64 + lane) * 8;
        bf16x8 bh = ld_frag(fWl1 + fo);
        c2[nt] = MFMA16(A2[ks], bh, c2[nt]);
        bh = ld_frag(fWr1 + fo);
        c2[nt] = MFMA16(X[ks], bh, c2[nt]);
        bh = ld_frag(fWl2 + fo);
        c3[nt] = MFMA16(A3[ks], bh, c3[nt]);
        bh = ld_frag(fWr2 + fo);
        c3[nt] = MFMA16(X[ks], bh, c3[nt]);
      }
    }
    float n2s[4] = {0,0,0,0}, n3s[4] = {0,0,0,0};
    #pragma unroll
    for (int nt = 0; nt < 4; ++nt) {
      float b2 = bl1[nt * 16 + m], b3 = bl2[nt * 16 + m];
      #pragma unroll
      for (int r = 0; r < 4; ++r) {
        c2[nt][r] += b2;
        c3[nt][r] += b3;
        n2s[r] = fmaf(c2[nt][r], c2[nt][r], n2s[r]);
        n3s[r] = fmaf(c3[nt][r], c3[nt][r], n3s[r]);
      }
    }
    #pragma unroll
    for (int off = 1; off < 16; off <<= 1)
      #pragma unroll
      for (int r = 0; r < 4; ++r) {
        n2s[r] += __shfl_xor(n2s[r], off);
        n3s[r] += __shfl_xor(n3s[r], off);
      }
    float r2v[4], r3v[4];
    #pragma unroll
    for (int r = 0; r < 4; ++r) {
      r2v[r] = 0.5f / fmaxf(sqrtf(n2s[r]), 1e-12f);
      r3v[r] = 0.5f / fmaxf(sqrtf(n3s[r]), 1e-12f);
    }
    float y[4][4];
    float s1[4] = {0,0,0,0}, s2[4] = {0,0,0,0};
    #pragma unroll
    for (int nt = 0; nt < 4; ++nt)
      #pragma unroll
      for (int r = 0; r < 4; ++r) {
        float v = fmaxf(fmaf(c2[nt][r], r2v[r], c3[nt][r] * r3v[r]), 0.0f);
        y[nt][r] = v;
        s1[r] += v;
        s2[r] = fmaf(v, v, s2[r]);
      }
    #pragma unroll
    for (int off = 1; off < 16; off <<= 1)
      #pragma unroll
      for (int r = 0; r < 4; ++r) {
        s1[r] += __shfl_xor(s1[r], off);
        s2[r] += __shfl_xor(s2[r], off);
      }
    float mean[4], sig[4];
    #pragma unroll
    for (int r = 0; r < 4; ++r) {
      mean[r] = s1[r] * (1.0f / H);
      float var = s2[r] * (1.0f / H) - mean[r] * mean[r];
      sig[r] = rsqrtf(var + 1e-5f);
    }
    unsigned int obits[4][4];
    #pragma unroll
    for (int nt = 0; nt < 4; ++nt) {
      float gv = g[nt * 16 + m], bv = bb[nt * 16 + m];
      #pragma unroll
      for (int r = 0; r < 4; ++r) {
        float o = (y[nt][r] - mean[r]) * sig[r] * gv + bv;
        obits[nt][r] = f2bf_bits(o);
        hout_s[(size_t)(r0 + q * 4 + r) * H + nt * 16 + m] = (ushort_t)obits[nt][r];
      }
    }
    if (final_l) {
      float wv[4];
      #pragma unroll
      for (int nt = 0; nt < 4; ++nt) wv[nt] = Wreg[nt * 16 + m];
      float p[4] = {0,0,0,0};
      #pragma unroll
      for (int nt = 0; nt < 4; ++nt)
        #pragma unroll
        for (int r = 0; r < 4; ++r)
          p[r] = fmaf(bf2f((ushort_t)obits[nt][r]), wv[nt], p[r]);
      #pragma unroll
      for (int off = 1; off < 16; off <<= 1)
        #pragma unroll
        for (int r = 0; r < 4; ++r) p[r] += __shfl_xor(p[r], off);
      if (m == 0) {
        float b0v = breg[0];
        #pragma unroll
        for (int r = 0; r < 4; ++r) reg_out[r0 + q * 4 + r] = p[r] + b0v;
      }
    }
  } else {
    // ---------------- pat side ----------------
    const int r0 = (blockIdx.x - SB2_STAY) * 128 + wid * 16;
    if (r0 < N_PAT) {   // windows never straddle (N_PAT % 16 == 0)
      #pragma unroll
      for (int t = 0; t < 2; ++t) {
        int ni = g8 + t * 8;   // 16 tasks: agg1 (stay->pat)
        gather_row(hin_s, off1, csr1, r0 + ni, wsl + ni * 144, fg);
      }
    }
    __syncthreads();
    if (r0 >= N_PAT) return;
    const ushort_t* ar = (const ushort_t*)(wsl + m * 144);
    const ushort_t* xp = hin_p + (size_t)(r0 + m) * H + q * 8;
    bf16x8 A[2], X[2];
    A[0] = ld_frag(ar + q * 8);  A[1] = ld_frag(ar + q * 8 + 32);
    X[0] = ld_frag(xp);          X[1] = ld_frag(xp + 32);
    f32x4 c[4] = {{0,0,0,0},{0,0,0,0},{0,0,0,0},{0,0,0,0}};
    #pragma unroll
    for (int nt = 0; nt < 4; ++nt) {
      #pragma unroll
      for (int ks = 0; ks < 2; ++ks) {
        const size_t fo = ((size_t)(nt * 2 + ks) * 64 + lane) * 8;
        bf16x8 bh = ld_frag(fWl0 + fo);
        c[nt] = MFMA16(A[ks], bh, c[nt]);
        bh = ld_frag(fWr0 + fo);
        c[nt] = MFMA16(X[ks], bh, c[nt]);
      }
    }
    float n2s[4] = {0, 0, 0, 0};
    #pragma unroll
    for (int nt = 0; nt < 4; ++nt) {
      float bias = bl0[nt * 16 + m];
      #pragma unroll
      for (int r = 0; r < 4; ++r) {
        c[nt][r] += bias;
        n2s[r] = fmaf(c[nt][r], c[nt][r], n2s[r]);
      }
    }
    #pragma unroll
    for (int off = 1; off < 16; off <<= 1)
      #pragma unroll
      for (int r = 0; r < 4; ++r) n2s[r] += __shfl_xor(n2s[r], off);
    float rv[4];
    #pragma unroll
    for (int r = 0; r < 4; ++r) rv[r] = 1.0f / fmaxf(sqrtf(n2s[r]), 1e-12f);
    float y[4][4];
    float s1[4] = {0,0,0,0}, s2[4] = {0,0,0,0};
    #pragma unroll
    for (int nt = 0; nt < 4; ++nt)
      #pragma unroll
      for (int r = 0; r < 4; ++r) {
        float v = fmaxf(c[nt][r] * rv[r], 0.0f);
        y[nt][r] = v;
        s1[r] += v;
        s2[r] = fmaf(v, v, s2[r]);
      }
    #pragma unroll
    for (int off = 1; off < 16; off <<= 1)
      #pragma unroll
      for (int r = 0; r < 4; ++r) {
        s1[r] += __shfl_xor(s1[r], off);
        s2[r] += __shfl_xor(s2[r], off);
      }
    float mean[4], sig[4];
    #pragma unroll
    for (int r = 0; r < 4; ++r) {
      mean[r] = s1[r] * (1.0f / H);
      float var = s2[r] * (1.0f / H) - mean[r] * mean[r];
      sig[r] = rsqrtf(var + 1e-5f);
    }
    #pragma unroll
    for (int nt = 0; nt < 4; ++nt) {
      float gv = g[nt * 16 + m], bv = bb[nt * 16 + m];
      #pragma unroll
      for (int r = 0; r < 4; ++r) {
        float o = (y[nt][r] - mean[r]) * sig[r] * gv + bv;
        hout_p[(size_t)(r0 + q * 4 + r) * H + nt * 16 + m] = (ushort_t)f2bf_bits(o);
      }
    }
  }
}

// -----------------------------------------------------------------------------

extern "C" void kernel_launch(void* const* d_in, const int* in_sizes, int n_in,
                              void* d_out, int out_size, void* d_ws, size_t ws_size,
                              hipStream_t stream) {
  const float* x_stay  = (const float*)d_in[0];
  const float* x_pat   = (const float*)d_in[1];
  const float* Wp_stay = (const float*)d_in[2];
  const float* bp_stay = (const float*)d_in[3];
  const float* Wp_pat  = (const float*)d_in[4];
  const float* bp_pat  = (const float*)d_in[5];
  const float* Wl      = (const float*)d_in[6];
  const float* bl      = (const float*)d_in[7];
  const float* Wr      = (const float*)d_in[8];
  const float* ln_g    = (const float*)d_in[9];
  const float* ln_b    = (const float*)d_in[10];
  const float* Wreg    = (const float*)d_in[11];
  const float* breg    = (const float*)d_in[12];
  const int* e1s = (const int*)d_in[13];
  const int* e1d = (const int*)d_in[14];
  const int* e2s = (const int*)d_in[15];
  const int* e2d = (const int*)d_in[16];
  const int* e3s = (const int*)d_in[17];
  const int* e3d = (const int*)d_in[18];
  float* out = (float*)d_out;

  const size_t S = (size_t)N_STAY * H;
  const size_t P = (size_t)N_PAT * H;

  // ping-pong hidden buffers (layer0: h0->h1, layer1: h1->h0)
  ushort_t* hs0  = (ushort_t*)d_ws;
  ushort_t* hp0  = hs0 + S;
  ushort_t* hs1  = hp0 + P;
  ushort_t* hp1  = hs1 + S;
  ushort_t* fragW = hp1 + P;
  ushort_t* fWpS = fragW;                // K=128: 2*8192
  ushort_t* fWpP = fragW + 16384;        // K=64:  2*4096
  ushort_t* fWlB = fragW + 24576;        // 6 * 8192
  ushort_t* fWrB = fragW + 24576 + 49152;
  int* ib    = (int*)(fragW + 122880);
  int* off1  = ib;                         // N_PAT+1
  int* off2  = off1 + (N_PAT + 1);         // N_STAY+1
  int* off3  = off2 + (N_STAY + 1);        // N_STAY+1
  int* bh1   = off3 + (N_STAY + 1);        // coarse hists, contiguous
  int* bh2   = bh1 + NBC_PAT;
  int* bh3   = bh2 + NBC_STAY;
  int* bo1   = bh3 + NBC_STAY;             // NBC_PAT+1
  int* bo2   = bo1 + (NBC_PAT + 1);        // NBC_STAY+1
  int* bo3   = bo2 + (NBC_STAY + 1);       // NBC_STAY+1
  int* bc1   = bo3 + (NBC_STAY + 1);       // cursors
  int* bc2   = bc1 + NBC_PAT;
  int* bc3   = bc2 + NBC_STAY;
  int* bv1   = bc3 + NBC_STAY;             // binned packed values, E each
  int* bv2   = bv1 + N_EDGE;
  int* bv3   = bv2 + N_EDGE;
  int* csr1  = bv3 + N_EDGE;               // E each
  int* csr2  = csr1 + N_EDGE;
  int* csr3  = csr2 + N_EDGE;

  // weight preconversion (tiny, one dispatch)
  precvt_all_kernel<<<30, 256, 0, stream>>>(Wp_stay, Wp_pat, Wl, Wr,
                                            fWpS, fWpP, fWlB, fWrB);

  // CSR build (R3-proven structure)
  hipMemsetAsync(bh1, 0, (size_t)(NBC_PAT + 2 * NBC_STAY) * sizeof(int), stream);
  blockhist3_kernel<<<3 * PB, 256, 0, stream>>>(e1d, e2d, e3d, bh1, bh2, bh3);
  scan3_kernel<<<3, 256, 0, stream>>>(bh1, bo1, bc1, bh2, bo2, bc2, bh3, bo3, bc3);
  phaseA3_kernel<<<3 * PB, 256, 0, stream>>>(e1s, e1d, e2s, e2d, e3s, e3d,
                                             bc1, bc2, bc3, bv1, bv2, bv3);
  phaseB3_kernel<<<NBC_PAT + 2 * NBC_STAY, 256, 0, stream>>>(
      bv1, bo1, bv2, bo2, bv3, bo3, csr1, off1, csr2, off2, csr3, off3);

  // input projections (coalesced LDS-transposed x, LDS weights)
  proj_both_kernel<<<SB2_STAY + SB2_PAT, 512, 0, stream>>>(
      x_stay, fWpS, bp_stay, x_pat, fWpP, bp_pat, hs0, hp0);

  for (int l = 0; l < 2; ++l) {
    ushort_t* fWl0 = fWlB + (size_t)(l * 3 + 0) * 8192;
    ushort_t* fWl1 = fWlB + (size_t)(l * 3 + 1) * 8192;
    ushort_t* fWl2 = fWlB + (size_t)(l * 3 + 2) * 8192;
    ushort_t* fWr0 = fWrB + (size_t)(l * 3 + 0) * 8192;
    ushort_t* fWr1 = fWrB + (size_t)(l * 3 + 1) * 8192;
    ushort_t* fWr2 = fWrB + (size_t)(l * 3 + 2) * 8192;
    const float* bl0 = bl + (size_t)(l * 3 + 0) * H;
    const float* bl1 = bl + (size_t)(l * 3 + 1) * H;
    const float* bl2 = bl + (size_t)(l * 3 + 2) * H;
    const float* g  = ln_g + (size_t)l * H;
    const float* bb = ln_b + (size_t)l * H;

    const ushort_t* hin_s = (l == 0) ? hs0 : hs1;
    const ushort_t* hin_p = (l == 0) ? hp0 : hp1;
    ushort_t* hout_s = (l == 0) ? hs1 : hs0;
    ushort_t* hout_p = (l == 0) ? hp1 : hp0;

    sage_fused_mfma<<<SB2_STAY + SB2_PAT, 512, 0, stream>>>(
        hin_s, hin_p, off1, csr1, off2, csr2, off3, csr3,
        fWl0, fWr0, fWl1, fWr1, fWl2, fWr2,
        bl0, bl1, bl2, g, bb,
        hout_p, hout_s, Wreg, breg, out, (l == 1) ? 1 : 0);
  }
}

// Round 12
// 459.678 us; speedup vs baseline: 1.0819x; 1.0135x over previous
//
#include <hip/hip_runtime.h>

#define H 64
#define N_STAY 200000
#define N_PAT  100000
#define N_EDGE 1000000
#define NBC_STAY 98    // ceil(200000/2048)
#define NBC_PAT  49    // ceil(100000/2048)
#define PB 245         // ceil(1e6/4096) edge blocks of 4096

#define SB2_STAY 1563  // ceil(200000/128) 512-thread blocks
#define SB2_PAT  782   // ceil(100000/128)

typedef unsigned short ushort_t;
typedef __attribute__((ext_vector_type(8))) short bf16x8;
typedef __attribute__((ext_vector_type(4))) float f32x4;
typedef __attribute__((ext_vector_type(2))) float f32x2;

__device__ __forceinline__ float bf2f(ushort_t u) {
  union { unsigned int i; float f; } c;
  c.i = ((unsigned int)u) << 16;
  return c.f;
}
__device__ __forceinline__ unsigned int f2bf_bits(float f) {
  union { float v; unsigned int i; } c; c.v = f;
  unsigned int r = c.i + 0x7fffu + ((c.i >> 16) & 1u);  // RNE
  return r >> 16;
}
__device__ __forceinline__ bf16x8 ld_frag(const ushort_t* p) {
  union { uint4 u; bf16x8 v; } c;
  c.u = *(const uint4*)p;
  return c.v;
}

// ---- agg helpers -----------------------------------------------------------

__device__ __forceinline__ f32x2 upk2(unsigned int u) {
  f32x2 r;
  r.x = __uint_as_float(u << 16);
  r.y = __uint_as_float(u & 0xffff0000u);
  return r;
}
__device__ __forceinline__ void fma2(f32x2& a, unsigned int u, float w) {
  a.x = fmaf(__uint_as_float(u << 16), w, a.x);
  a.y = fmaf(__uint_as_float(u & 0xffff0000u), w, a.y);
}
__device__ __forceinline__ unsigned int cvtpk_bf16(float lo, float hi) {
  unsigned int r;
  asm("v_cvt_pk_bf16_f32 %0, %1, %2" : "=v"(r) : "v"(lo), "v"(hi));
  return r;
}

// gather mean of neighbor rows into one 128B LDS row (8 lanes cooperate,
// lane covers bytes [fg*16, fg*16+16)). Identical math to the old agg kernel
// (4-deep unroll, masked fma tail, rcp mean, cvt_pk pack) -> bitwise-same agg.
__device__ __forceinline__
void gather_row(const ushort_t* __restrict__ x, const int* __restrict__ off,
                const int* __restrict__ csr, int node,
                char* __restrict__ row, int fg) {
  const int o0 = off[node], o1 = off[node + 1];
  const char* xb = (const char*)x + (fg << 4);
  f32x2 a0 = {0.f,0.f}, a1 = {0.f,0.f}, a2 = {0.f,0.f}, a3 = {0.f,0.f};
  f32x2 b0 = {0.f,0.f}, b1 = {0.f,0.f}, b2 = {0.f,0.f}, b3 = {0.f,0.f};
  int t = o0;
  int s0 = (t     < o1) ? csr[t]     : 0;
  int s1 = (t + 1 < o1) ? csr[t + 1] : 0;
  int s2 = (t + 2 < o1) ? csr[t + 2] : 0;
  int s3 = (t + 3 < o1) ? csr[t + 3] : 0;
  while (t < o1) {
    uint4 qa = *(const uint4*)(xb + ((unsigned)s0 << 7));
    uint4 qb = *(const uint4*)(xb + ((unsigned)s1 << 7));
    uint4 qc = *(const uint4*)(xb + ((unsigned)s2 << 7));
    uint4 qd = *(const uint4*)(xb + ((unsigned)s3 << 7));
    const float w1 = (t + 1 < o1) ? 1.0f : 0.0f;
    const float w2 = (t + 2 < o1) ? 1.0f : 0.0f;
    const float w3 = (t + 3 < o1) ? 1.0f : 0.0f;
    int t4 = t + 4;
    s0 = (t4     < o1) ? csr[t4]     : 0;
    s1 = (t4 + 1 < o1) ? csr[t4 + 1] : 0;
    s2 = (t4 + 2 < o1) ? csr[t4 + 2] : 0;
    s3 = (t4 + 3 < o1) ? csr[t4 + 3] : 0;
    a0 += upk2(qa.x); a1 += upk2(qa.y); a2 += upk2(qa.z); a3 += upk2(qa.w);
    fma2(b0, qb.x, w1); fma2(b1, qb.y, w1); fma2(b2, qb.z, w1); fma2(b3, qb.w, w1);
    fma2(a0, qc.x, w2); fma2(a1, qc.y, w2); fma2(a2, qc.z, w2); fma2(a3, qc.w, w2);
    fma2(b0, qd.x, w3); fma2(b1, qd.y, w3); fma2(b2, qd.z, w3); fma2(b3, qd.w, w3);
    t = t4;
  }
  a0 += b0; a1 += b1; a2 += b2; a3 += b3;
  const float inv = __builtin_amdgcn_rcpf(fmaxf((float)(o1 - o0), 1.0f));
  uint4 q;
  q.x = cvtpk_bf16(a0.x * inv, a0.y * inv);
  q.y = cvtpk_bf16(a1.x * inv, a1.y * inv);
  q.z = cvtpk_bf16(a2.x * inv, a2.y * inv);
  q.w = cvtpk_bf16(a3.x * inv, a3.y * inv);
  *(uint4*)(row + fg * 16) = q;
}

// ---------------- CSR build -------------------------------------------------

__global__ __launch_bounds__(256)
void blockhist3_kernel(const int* __restrict__ d1, const int* __restrict__ d2,
                       const int* __restrict__ d3,
                       int* __restrict__ h1, int* __restrict__ h2, int* __restrict__ h3) {
  int which = blockIdx.x / PB;
  int blk = blockIdx.x % PB;
  const int* dp = (which == 0) ? d1 : (which == 1) ? d2 : d3;
  int* hp = (which == 0) ? h1 : (which == 1) ? h2 : h3;
  int nbc = (which == 0) ? NBC_PAT : NBC_STAY;
  __shared__ int lh[128];
  if (threadIdx.x < 128) lh[threadIdx.x] = 0;
  __syncthreads();
  int base = blk * 4096;
  int n = min(4096, N_EDGE - base);
  for (int i = threadIdx.x; i < n; i += 256)
    atomicAdd(&lh[dp[base + i] >> 11], 1);
  __syncthreads();
  if (threadIdx.x < nbc && lh[threadIdx.x])
    atomicAdd(&hp[threadIdx.x], lh[threadIdx.x]);
}

// single-block exclusive scan body, n <= 4096; writes off[0..n] and cur[0..n-1]
__device__ __forceinline__
void scan_dev(const int* __restrict__ in, int n, int* __restrict__ off,
              int* __restrict__ cur, int total) {
  int tid = threadIdx.x;
  int base = tid * 16;
  int vals[16]; int s = 0;
  #pragma unroll
  for (int i = 0; i < 16; ++i) {
    int idx = base + i;
    vals[i] = (idx < n) ? in[idx] : 0;
    s += vals[i];
  }
  int lane = tid & 63, w = tid >> 6;
  int incl = s;
  #pragma unroll
  for (int o = 1; o < 64; o <<= 1) {
    int t = __shfl_up(incl, o);
    if (lane >= o) incl += t;
  }
  __shared__ int wtot[4];
  if (lane == 63) wtot[w] = incl;
  __syncthreads();
  int wbase = 0;
  for (int i = 0; i < w; ++i) wbase += wtot[i];
  int run = wbase + incl - s;
  #pragma unroll
  for (int i = 0; i < 16; ++i) {
    int idx = base + i;
    if (idx < n) { off[idx] = run; cur[idx] = run; run += vals[i]; }
  }
  if (tid == 0) off[n] = total;
}

// three coarse-hist scans in one dispatch (block = which)
__global__ __launch_bounds__(256)
void scan3_kernel(const int* __restrict__ bh1, int* __restrict__ bo1, int* __restrict__ bc1,
                  const int* __restrict__ bh2, int* __restrict__ bo2, int* __restrict__ bc2,
                  const int* __restrict__ bh3, int* __restrict__ bo3, int* __restrict__ bc3) {
  if (blockIdx.x == 0)      scan_dev(bh1, NBC_PAT,  bo1, bc1, N_EDGE);
  else if (blockIdx.x == 1) scan_dev(bh2, NBC_STAY, bo2, bc2, N_EDGE);
  else                      scan_dev(bh3, NBC_STAY, bo3, bc3, N_EDGE);
}

// packed value = src | ((dst & 2047) << 18); bucket = dst >> 11
__global__ __launch_bounds__(256)
void phaseA3_kernel(const int* __restrict__ s1, const int* __restrict__ d1,
                    const int* __restrict__ s2, const int* __restrict__ d2,
                    const int* __restrict__ s3, const int* __restrict__ d3,
                    int* __restrict__ c1, int* __restrict__ c2, int* __restrict__ c3,
                    int* __restrict__ v1, int* __restrict__ v2, int* __restrict__ v3) {
  int which = blockIdx.x / PB;
  int blk = blockIdx.x % PB;
  const int* sp = (which == 0) ? s1 : (which == 1) ? s2 : s3;
  const int* dp = (which == 0) ? d1 : (which == 1) ? d2 : d3;
  int* cp = (which == 0) ? c1 : (which == 1) ? c2 : c3;
  int* vp = (which == 0) ? v1 : (which == 1) ? v2 : v3;
  int nbc = (which == 0) ? NBC_PAT : NBC_STAY;
  __shared__ int vals[4096];
  __shared__ unsigned char bkt[4096];
  __shared__ int lh[128], lbase[128], lcur[128], gbase[128];
  __shared__ int wt[2];
  const int tid = threadIdx.x;
  if (tid < 128) lh[tid] = 0;
  __syncthreads();
  int base = blk * 4096;
  int n = min(4096, N_EDGE - base);
  int pv[16], pbk[16];
  #pragma unroll
  for (int i = 0; i < 16; ++i) {
    int idx = i * 256 + tid;
    if (idx < n) {
      int e = base + idx;
      int d = dp[e], s = sp[e];
      pv[i] = s | ((d & 2047) << 18);
      pbk[i] = d >> 11;
      atomicAdd(&lh[pbk[i]], 1);
    } else pbk[i] = -1;
  }
  __syncthreads();
  // exclusive scan of lh[0..nbc) (nbc <= 98 < 128) via two waves
  {
    int lane = tid & 63, w = tid >> 6;
    int x = (tid < 128 && tid < nbc) ? lh[tid] : 0;
    int incl = x;
    #pragma unroll
    for (int o = 1; o < 64; o <<= 1) {
      int t = __shfl_up(incl, o);
      if (lane >= o) incl += t;
    }
    if (w < 2 && lane == 63) wt[w] = incl;
    __syncthreads();
    if (tid < 128) {
      int ex = incl - x + ((w == 1) ? wt[0] : 0);
      lbase[tid] = ex;
      lcur[tid] = ex;
    }
  }
  __syncthreads();
  // place into LDS sorted by bucket
  #pragma unroll
  for (int i = 0; i < 16; ++i) {
    if (pbk[i] >= 0) {
      int r = atomicAdd(&lcur[pbk[i]], 1);
      vals[r] = pv[i];
      bkt[r] = (unsigned char)pbk[i];
    }
  }
  __syncthreads();
  // reserve global space: one atomic per non-empty bucket group
  if (tid < nbc) {
    int cnt = lh[tid];
    gbase[tid] = cnt ? atomicAdd(&cp[tid], cnt) : 0;
  }
  __syncthreads();
  // contiguous run copy-out (consecutive i -> mostly consecutive addresses)
  for (int i = tid; i < n; i += 256) {
    int b = bkt[i];
    vp[gbase[b] + i - lbase[b]] = vals[i];
  }
}

// one block per coarse bucket: node-sorted csr + off[]
__global__ __launch_bounds__(256)
void phaseB3_kernel(const int* __restrict__ v1, const int* __restrict__ bo1,
                    const int* __restrict__ v2, const int* __restrict__ bo2,
                    const int* __restrict__ v3, const int* __restrict__ bo3,
                    int* __restrict__ csr1, int* __restrict__ off1,
                    int* __restrict__ csr2, int* __restrict__ off2,
                    int* __restrict__ csr3, int* __restrict__ off3) {
  int b = blockIdx.x;
  const int* v; const int* bo; int* csr; int* off; int N; int lb;
  if (b < NBC_PAT)                 { v = v1; bo = bo1; csr = csr1; off = off1; N = N_PAT;  lb = b; }
  else if (b < NBC_PAT + NBC_STAY) { v = v2; bo = bo2; csr = csr2; off = off2; N = N_STAY; lb = b - NBC_PAT; }
  else                             { v = v3; bo = bo3; csr = csr3; off = off3; N = N_STAY; lb = b - NBC_PAT - NBC_STAY; }
  const int tid = threadIdx.x;
  __shared__ int lh[2048];
  __shared__ int lcur[2048];
  __shared__ int wt[4];
  #pragma unroll
  for (int j = 0; j < 8; ++j) lh[tid + j * 256] = 0;
  __syncthreads();
  const int rb = bo[lb], re = bo[lb + 1];
  for (int i = rb + tid; i < re; i += 256)
    atomicAdd(&lh[(v[i] >> 18) & 2047], 1);
  __syncthreads();
  // block exclusive scan over 2048 -> lcur (+rb), emit off[]
  const int node_base = lb * 2048;
  const int b8 = tid * 8;
  int ex[8]; int run = 0;
  #pragma unroll
  for (int j = 0; j < 8; ++j) { ex[j] = run; run += lh[b8 + j]; }
  int lane = tid & 63, w = tid >> 6;
  int incl = run;
  #pragma unroll
  for (int o = 1; o < 64; o <<= 1) {
    int t = __shfl_up(incl, o);
    if (lane >= o) incl += t;
  }
  if (lane == 63) wt[w] = incl;
  __syncthreads();
  int wb = 0;
  for (int i = 0; i < w; ++i) wb += wt[i];
  const int tex = rb + wb + incl - run;
  #pragma unroll
  for (int j = 0; j < 8; ++j) {
    int pos = tex + ex[j];
    lcur[b8 + j] = pos;
    int node = node_base + b8 + j;
    if (node < N) off[node] = pos;
  }
  __syncthreads();
  for (int i = rb + tid; i < re; i += 256) {
    int val = v[i];
    int pos = atomicAdd(&lcur[(val >> 18) & 2047], 1);
    csr[pos] = val & 0x3FFFF;
  }
  if (b == 0 && tid == 0) {
    off1[N_PAT] = N_EDGE;
    off2[N_STAY] = N_EDGE;
    off3[N_STAY] = N_EDGE;
  }
}

// ---------------- weight preconversion to MFMA B-fragments (hi+lo bf16) -----

template<int K>
__device__ __forceinline__
void precvt_dev(const float* __restrict__ src, ushort_t* __restrict__ dst,
                int nmat, int blk) {
  const int KS = K / 32;
  const int FU = KS * 4;
  const int PLANE = FU * 64 * 8;
  int fu = blk * 4 + (threadIdx.x >> 6);
  int lane = threadIdx.x & 63;
  int mi = fu / FU;
  if (mi >= nmat) return;
  int fid = fu % FU;
  int ntile = fid / KS;
  int kstep = fid % KS;
  int q = lane >> 4, n = ntile * 16 + (lane & 15);
  const float* W = src + (size_t)mi * K * H;
  union { ushort_t s[8]; uint4 u; } hi, lo;
  #pragma unroll
  for (int j = 0; j < 8; ++j) {
    float v = W[(size_t)(kstep * 32 + q * 8 + j) * H + n];
    unsigned hb = f2bf_bits(v);
    hi.s[j] = (ushort_t)hb;
    lo.s[j] = (ushort_t)f2bf_bits(v - bf2f((ushort_t)hb));
  }
  ushort_t* base = dst + (size_t)mi * 2 * PLANE + ((size_t)fid * 64 + lane) * 8;
  *(uint4*)base = hi.u;
  *(uint4*)(base + PLANE) = lo.u;
}

// blocks [0,4)=WpS, [4,6)=WpP, [6,18)=Wl (6 mats), [18,30)=Wr (6 mats)
__global__ __launch_bounds__(256)
void precvt_all_kernel(const float* __restrict__ WpS, const float* __restrict__ WpP,
                       const float* __restrict__ Wl, const float* __restrict__ Wr,
                       ushort_t* __restrict__ fWpS, ushort_t* __restrict__ fWpP,
                       ushort_t* __restrict__ fWlB, ushort_t* __restrict__ fWrB) {
  int b = blockIdx.x;
  if (b < 4)        precvt_dev<128>(WpS, fWpS, 1, b);
  else if (b < 6)   precvt_dev<64>(WpP, fWpP, 1, b - 4);
  else if (b < 18)  precvt_dev<64>(Wl, fWlB, 6, b - 6);
  else              precvt_dev<64>(Wr, fWrB, 6, b - 18);
}

// ---------------- MFMA dense kernels ----------------------------------------

#define MFMA16(a, b, c) __builtin_amdgcn_mfma_f32_16x16x32_bf16((a), (b), (c), 0, 0, 0)

// proj: coalesced x via per-wave LDS transpose staging + LDS weights (R11)
template<int K>
__device__ __forceinline__
void proj_lds_dev(const float* __restrict__ x, const ushort_t* __restrict__ fw,
                  const float* __restrict__ b, ushort_t* __restrict__ y,
                  int N, int blk, uint4* __restrict__ u4, float* __restrict__ xs) {
  const int KS = K / 32;
  const int PLANE = KS * 4 * 64 * 8;       // ushorts per plane
  const int NU4 = PLANE / 4;               // uint4 count covering both planes
  const int tid = threadIdx.x;
  for (int i = tid; i < NU4; i += 512)
    u4[i] = ((const uint4*)fw)[i];
  __syncthreads();
  const ushort_t* w = (const ushort_t*)u4;
  const int wid = tid >> 6, lane = tid & 63;
  const int r0 = blk * 128 + wid * 16;
  if (r0 >= N) return;                     // after the barrier: safe
  const int m = lane & 15, q = lane >> 4;
  const int lr = lane >> 2, lc = lane & 3;
  float* sl = xs + wid * 576;              // 16 rows x 36 dwords per wave
  const float* xrow = x + (size_t)(r0 + lr) * K + lc * 4;
  float* wr0 = sl + lr * 36 + lc * 4;
  float* wr1 = wr0 + 16;
  const float* rd = sl + m * 36 + q * 8;
  f32x4 c[4] = {{0,0,0,0},{0,0,0,0},{0,0,0,0},{0,0,0,0}};
  float4 va = *(const float4*)xrow;
  float4 vb = *(const float4*)(xrow + 16);
  #pragma unroll
  for (int ks = 0; ks < KS; ++ks) {
    *(float4*)wr0 = va;
    *(float4*)wr1 = vb;
    if (ks + 1 < KS) {
      va = *(const float4*)(xrow + (ks + 1) * 32);
      vb = *(const float4*)(xrow + (ks + 1) * 32 + 16);
    }
    float4 v0 = *(const float4*)rd;
    float4 v1 = *(const float4*)(rd + 4);
    float vv[8] = {v0.x, v0.y, v0.z, v0.w, v1.x, v1.y, v1.z, v1.w};
    union { ushort_t s[8]; bf16x8 v; } ah, al;
    #pragma unroll
    for (int j = 0; j < 8; ++j) {
      unsigned hb = f2bf_bits(vv[j]);
      ah.s[j] = (ushort_t)hb;
      al.s[j] = (ushort_t)f2bf_bits(vv[j] - bf2f((ushort_t)hb));
    }
    #pragma unroll
    for (int nt = 0; nt < 4; ++nt) {
      const ushort_t* fb = w + ((size_t)(nt * KS + ks) * 64 + lane) * 8;
      bf16x8 bh = ld_frag(fb);
      bf16x8 blo = ld_frag(fb + PLANE);
      c[nt] = MFMA16(ah.v, bh, c[nt]);
      c[nt] = MFMA16(ah.v, blo, c[nt]);
      c[nt] = MFMA16(al.v, bh, c[nt]);
    }
  }
  #pragma unroll
  for (int nt = 0; nt < 4; ++nt) {
    float bias = b[nt * 16 + m];
    #pragma unroll
    for (int r = 0; r < 4; ++r) {
      float o = fmaxf(c[nt][r] + bias, 0.0f);
      y[(size_t)(r0 + q * 4 + r) * H + nt * 16 + m] = (ushort_t)f2bf_bits(o);
    }
  }
}

// both projections in one dispatch: blocks [0,SB2_STAY)=stay K=128, rest pat K=64
__global__ __launch_bounds__(512)
void proj_both_kernel(const float* __restrict__ xs_in, const ushort_t* __restrict__ fws,
                      const float* __restrict__ bs,
                      const float* __restrict__ xp_in, const ushort_t* __restrict__ fwp,
                      const float* __restrict__ bp,
                      ushort_t* __restrict__ ys, ushort_t* __restrict__ yp) {
  __shared__ uint4 u4[2048];      // 32KB weights
  __shared__ float xtile[4608];   // 18KB: 8 waves x 16 rows x 36 dwords
  if (blockIdx.x < SB2_STAY)
    proj_lds_dev<128>(xs_in, fws, bs, ys, N_STAY, blockIdx.x, u4, xtile);
  else
    proj_lds_dev<64>(xp_in, fwp, bp, yp, N_PAT, blockIdx.x - SB2_STAY, u4, xtile);
}

// ---------------- FUSED agg + SAGE layer: stay + pat in ONE dispatch ---------
// R12: final layer launches with SB2_STAY blocks only — reference never
// consumes the final hp (new_p dead in last layer), so the pat side (incl.
// the 1M-edge agg1 gather) is dead work there. Final hout_s store is also
// dead (only the fused regression head output is live) and is skipped.

__global__ __launch_bounds__(512)
void sage_fused_mfma(const ushort_t* __restrict__ hin_s, const ushort_t* __restrict__ hin_p,
                     const int* __restrict__ off1, const int* __restrict__ csr1,
                     const int* __restrict__ off2, const int* __restrict__ csr2,
                     const int* __restrict__ off3, const int* __restrict__ csr3,
                     const ushort_t* __restrict__ fWl0, const ushort_t* __restrict__ fWr0,
                     const ushort_t* __restrict__ fWl1, const ushort_t* __restrict__ fWr1,
                     const ushort_t* __restrict__ fWl2, const ushort_t* __restrict__ fWr2,
                     const float* __restrict__ bl0, const float* __restrict__ bl1,
                     const float* __restrict__ bl2,
                     const float* __restrict__ g, const float* __restrict__ bb,
                     ushort_t* __restrict__ hout_p, ushort_t* __restrict__ hout_s,
                     const float* __restrict__ Wreg, const float* __restrict__ breg,
                     float* __restrict__ reg_out, int final_l) {
  __shared__ __align__(16) char aggL[8 * 4608];   // 36,864 B
  const int tid = threadIdx.x;
  const int wid = tid >> 6, lane = tid & 63;
  const int m = lane & 15, q = lane >> 4;
  const int g8 = lane >> 3, fg = lane & 7;
  char* wsl = aggL + wid * 4608;

  if (blockIdx.x < SB2_STAY) {
    // ---------------- stay side ----------------
    const int r0 = blockIdx.x * 128 + wid * 16;   // wave window [r0, r0+16)
    if (r0 < N_STAY) {   // windows never straddle (N_STAY % 16 == 0)
      #pragma unroll
      for (int t = 0; t < 4; ++t) {
        int task = g8 + t * 8;
        int type = task >> 4;      // 0: agg2 (pat->stay), 1: agg3 (stay->stay)
        int ni = task & 15;
        char* row = wsl + type * 2304 + ni * 144;
        if (type == 0) gather_row(hin_p, off2, csr2, r0 + ni, row, fg);
        else           gather_row(hin_s, off3, csr3, r0 + ni, row, fg);
      }
    }
    __syncthreads();
    if (r0 >= N_STAY) return;
    const ushort_t* a2r = (const ushort_t*)(wsl + m * 144);
    const ushort_t* a3r = (const ushort_t*)(wsl + 2304 + m * 144);
    const ushort_t* xp  = hin_s + (size_t)(r0 + m) * H + q * 8;
    bf16x8 A2[2], A3[2], X[2];
    A2[0] = ld_frag(a2r + q * 8);  A2[1] = ld_frag(a2r + q * 8 + 32);
    A3[0] = ld_frag(a3r + q * 8);  A3[1] = ld_frag(a3r + q * 8 + 32);
    X[0]  = ld_frag(xp);           X[1]  = ld_frag(xp + 32);
    f32x4 c2[4] = {{0,0,0,0},{0,0,0,0},{0,0,0,0},{0,0,0,0}};
    f32x4 c3[4] = {{0,0,0,0},{0,0,0,0},{0,0,0,0},{0,0,0,0}};
    #pragma unroll
    for (int nt = 0; nt < 4; ++nt) {
      #pragma unroll
      for (int ks = 0; ks < 2; ++ks) {
        const size_t fo = ((size_t)(nt * 2 + ks) * 64 + lane) * 8;
        bf16x8 bh = ld_frag(fWl1 + fo);
        c2[nt] = MFMA16(A2[ks], bh, c2[nt]);
        bh = ld_frag(fWr1 + fo);
        c2[nt] = MFMA16(X[ks], bh, c2[nt]);
        bh = ld_frag(fWl2 + fo);
        c3[nt] = MFMA16(A3[ks], bh, c3[nt]);
        bh = ld_frag(fWr2 + fo);
        c3[nt] = MFMA16(X[ks], bh, c3[nt]);
      }
    }
    float n2s[4] = {0,0,0,0}, n3s[4] = {0,0,0,0};
    #pragma unroll
    for (int nt = 0; nt < 4; ++nt) {
      float b2 = bl1[nt * 16 + m], b3 = bl2[nt * 16 + m];
      #pragma unroll
      for (int r = 0; r < 4; ++r) {
        c2[nt][r] += b2;
        c3[nt][r] += b3;
        n2s[r] = fmaf(c2[nt][r], c2[nt][r], n2s[r]);
        n3s[r] = fmaf(c3[nt][r], c3[nt][r], n3s[r]);
      }
    }
    #pragma unroll
    for (int off = 1; off < 16; off <<= 1)
      #pragma unroll
      for (int r = 0; r < 4; ++r) {
        n2s[r] += __shfl_xor(n2s[r], off);
        n3s[r] += __shfl_xor(n3s[r], off);
      }
    float r2v[4], r3v[4];
    #pragma unroll
    for (int r = 0; r < 4; ++r) {
      r2v[r] = 0.5f / fmaxf(sqrtf(n2s[r]), 1e-12f);
      r3v[r] = 0.5f / fmaxf(sqrtf(n3s[r]), 1e-12f);
    }
    float y[4][4];
    float s1[4] = {0,0,0,0}, s2[4] = {0,0,0,0};
    #pragma unroll
    for (int nt = 0; nt < 4; ++nt)
      #pragma unroll
      for (int r = 0; r < 4; ++r) {
        float v = fmaxf(fmaf(c2[nt][r], r2v[r], c3[nt][r] * r3v[r]), 0.0f);
        y[nt][r] = v;
        s1[r] += v;
        s2[r] = fmaf(v, v, s2[r]);
      }
    #pragma unroll
    for (int off = 1; off < 16; off <<= 1)
      #pragma unroll
      for (int r = 0; r < 4; ++r) {
        s1[r] += __shfl_xor(s1[r], off);
        s2[r] += __shfl_xor(s2[r], off);
      }
    float mean[4], sig[4];
    #pragma unroll
    for (int r = 0; r < 4; ++r) {
      mean[r] = s1[r] * (1.0f / H);
      float var = s2[r] * (1.0f / H) - mean[r] * mean[r];
      sig[r] = rsqrtf(var + 1e-5f);
    }
    unsigned int obits[4][4];
    #pragma unroll
    for (int nt = 0; nt < 4; ++nt) {
      float gv = g[nt * 16 + m], bv = bb[nt * 16 + m];
      #pragma unroll
      for (int r = 0; r < 4; ++r) {
        float o = (y[nt][r] - mean[r]) * sig[r] * gv + bv;
        obits[nt][r] = f2bf_bits(o);
      }
    }
    if (!final_l) {
      #pragma unroll
      for (int nt = 0; nt < 4; ++nt)
        #pragma unroll
        for (int r = 0; r < 4; ++r)
          hout_s[(size_t)(r0 + q * 4 + r) * H + nt * 16 + m] = (ushort_t)obits[nt][r];
    } else {
      float wv[4];
      #pragma unroll
      for (int nt = 0; nt < 4; ++nt) wv[nt] = Wreg[nt * 16 + m];
      float p[4] = {0,0,0,0};
      #pragma unroll
      for (int nt = 0; nt < 4; ++nt)
        #pragma unroll
        for (int r = 0; r < 4; ++r)
          p[r] = fmaf(bf2f((ushort_t)obits[nt][r]), wv[nt], p[r]);
      #pragma unroll
      for (int off = 1; off < 16; off <<= 1)
        #pragma unroll
        for (int r = 0; r < 4; ++r) p[r] += __shfl_xor(p[r], off);
      if (m == 0) {
        float b0v = breg[0];
        #pragma unroll
        for (int r = 0; r < 4; ++r) reg_out[r0 + q * 4 + r] = p[r] + b0v;
      }
    }
  } else {
    // ---------------- pat side (never launched when final_l) ----------------
    const int r0 = (blockIdx.x - SB2_STAY) * 128 + wid * 16;
    if (r0 < N_PAT) {   // windows never straddle (N_PAT % 16 == 0)
      #pragma unroll
      for (int t = 0; t < 2; ++t) {
        int ni = g8 + t * 8;   // 16 tasks: agg1 (stay->pat)
        gather_row(hin_s, off1, csr1, r0 + ni, wsl + ni * 144, fg);
      }
    }
    __syncthreads();
    if (r0 >= N_PAT) return;
    const ushort_t* ar = (const ushort_t*)(wsl + m * 144);
    const ushort_t* xp = hin_p + (size_t)(r0 + m) * H + q * 8;
    bf16x8 A[2], X[2];
    A[0] = ld_frag(ar + q * 8);  A[1] = ld_frag(ar + q * 8 + 32);
    X[0] = ld_frag(xp);          X[1] = ld_frag(xp + 32);
    f32x4 c[4] = {{0,0,0,0},{0,0,0,0},{0,0,0,0},{0,0,0,0}};
    #pragma unroll
    for (int nt = 0; nt < 4; ++nt) {
      #pragma unroll
      for (int ks = 0; ks < 2; ++ks) {
        const size_t fo = ((size_t)(nt * 2 + ks) * 64 + lane) * 8;
        bf16x8 bh = ld_frag(fWl0 + fo);
        c[nt] = MFMA16(A[ks], bh, c[nt]);
        bh = ld_frag(fWr0 + fo);
        c[nt] = MFMA16(X[ks], bh, c[nt]);
      }
    }
    float n2s[4] = {0, 0, 0, 0};
    #pragma unroll
    for (int nt = 0; nt < 4; ++nt) {
      float bias = bl0[nt * 16 + m];
      #pragma unroll
      for (int r = 0; r < 4; ++r) {
        c[nt][r] += bias;
        n2s[r] = fmaf(c[nt][r], c[nt][r], n2s[r]);
      }
    }
    #pragma unroll
    for (int off = 1; off < 16; off <<= 1)
      #pragma unroll
      for (int r = 0; r < 4; ++r) n2s[r] += __shfl_xor(n2s[r], off);
    float rv[4];
    #pragma unroll
    for (int r = 0; r < 4; ++r) rv[r] = 1.0f / fmaxf(sqrtf(n2s[r]), 1e-12f);
    float y[4][4];
    float s1[4] = {0,0,0,0}, s2[4] = {0,0,0,0};
    #pragma unroll
    for (int nt = 0; nt < 4; ++nt)
      #pragma unroll
      for (int r = 0; r < 4; ++r) {
        float v = fmaxf(c[nt][r] * rv[r], 0.0f);
        y[nt][r] = v;
        s1[r] += v;
        s2[r] = fmaf(v, v, s2[r]);
      }
    #pragma unroll
    for (int off = 1; off < 16; off <<= 1)
      #pragma unroll
      for (int r = 0; r < 4; ++r) {
        s1[r] += __shfl_xor(s1[r], off);
        s2[r] += __shfl_xor(s2[r], off);
      }
    float mean[4], sig[4];
    #pragma unroll
    for (int r = 0; r < 4; ++r) {
      mean[r] = s1[r] * (1.0f / H);
      float var = s2[r] * (1.0f / H) - mean[r] * mean[r];
      sig[r] = rsqrtf(var + 1e-5f);
    }
    #pragma unroll
    for (int nt = 0; nt < 4; ++nt) {
      float gv = g[nt * 16 + m], bv = bb[nt * 16 + m];
      #pragma unroll
      for (int r = 0; r < 4; ++r) {
        float o = (y[nt][r] - mean[r]) * sig[r] * gv + bv;
        hout_p[(size_t)(r0 + q * 4 + r) * H + nt * 16 + m] = (ushort_t)f2bf_bits(o);
      }
    }
  }
}

// -----------------------------------------------------------------------------

extern "C" void kernel_launch(void* const* d_in, const int* in_sizes, int n_in,
                              void* d_out, int out_size, void* d_ws, size_t ws_size,
                              hipStream_t stream) {
  const float* x_stay  = (const float*)d_in[0];
  const float* x_pat   = (const float*)d_in[1];
  const float* Wp_stay = (const float*)d_in[2];
  const float* bp_stay = (const float*)d_in[3];
  const float* Wp_pat  = (const float*)d_in[4];
  const float* bp_pat  = (const float*)d_in[5];
  const float* Wl      = (const float*)d_in[6];
  const float* bl      = (const float*)d_in[7];
  const float* Wr      = (const float*)d_in[8];
  const float* ln_g    = (const float*)d_in[9];
  const float* ln_b    = (const float*)d_in[10];
  const float* Wreg    = (const float*)d_in[11];
  const float* breg    = (const float*)d_in[12];
  const int* e1s = (const int*)d_in[13];
  const int* e1d = (const int*)d_in[14];
  const int* e2s = (const int*)d_in[15];
  const int* e2d = (const int*)d_in[16];
  const int* e3s = (const int*)d_in[17];
  const int* e3d = (const int*)d_in[18];
  float* out = (float*)d_out;

  const size_t S = (size_t)N_STAY * H;
  const size_t P = (size_t)N_PAT * H;

  // ping-pong hidden buffers (layer0: h0->h1, layer1: h1->h0)
  ushort_t* hs0  = (ushort_t*)d_ws;
  ushort_t* hp0  = hs0 + S;
  ushort_t* hs1  = hp0 + P;
  ushort_t* hp1  = hs1 + S;
  ushort_t* fragW = hp1 + P;
  ushort_t* fWpS = fragW;                // K=128: 2*8192
  ushort_t* fWpP = fragW + 16384;        // K=64:  2*4096
  ushort_t* fWlB = fragW + 24576;        // 6 * 8192
  ushort_t* fWrB = fragW + 24576 + 49152;
  int* ib    = (int*)(fragW + 122880);
  int* off1  = ib;                         // N_PAT+1
  int* off2  = off1 + (N_PAT + 1);         // N_STAY+1
  int* off3  = off2 + (N_STAY + 1);        // N_STAY+1
  int* bh1   = off3 + (N_STAY + 1);        // coarse hists, contiguous
  int* bh2   = bh1 + NBC_PAT;
  int* bh3   = bh2 + NBC_STAY;
  int* bo1   = bh3 + NBC_STAY;             // NBC_PAT+1
  int* bo2   = bo1 + (NBC_PAT + 1);        // NBC_STAY+1
  int* bo3   = bo2 + (NBC_STAY + 1);       // NBC_STAY+1
  int* bc1   = bo3 + (NBC_STAY + 1);       // cursors
  int* bc2   = bc1 + NBC_PAT;
  int* bc3   = bc2 + NBC_STAY;
  int* bv1   = bc3 + NBC_STAY;             // binned packed values, E each
  int* bv2   = bv1 + N_EDGE;
  int* bv3   = bv2 + N_EDGE;
  int* csr1  = bv3 + N_EDGE;               // E each
  int* csr2  = csr1 + N_EDGE;
  int* csr3  = csr2 + N_EDGE;

  // weight preconversion (tiny, one dispatch)
  precvt_all_kernel<<<30, 256, 0, stream>>>(Wp_stay, Wp_pat, Wl, Wr,
                                            fWpS, fWpP, fWlB, fWrB);

  // CSR build (R3-proven structure)
  hipMemsetAsync(bh1, 0, (size_t)(NBC_PAT + 2 * NBC_STAY) * sizeof(int), stream);
  blockhist3_kernel<<<3 * PB, 256, 0, stream>>>(e1d, e2d, e3d, bh1, bh2, bh3);
  scan3_kernel<<<3, 256, 0, stream>>>(bh1, bo1, bc1, bh2, bo2, bc2, bh3, bo3, bc3);
  phaseA3_kernel<<<3 * PB, 256, 0, stream>>>(e1s, e1d, e2s, e2d, e3s, e3d,
                                             bc1, bc2, bc3, bv1, bv2, bv3);
  phaseB3_kernel<<<NBC_PAT + 2 * NBC_STAY, 256, 0, stream>>>(
      bv1, bo1, bv2, bo2, bv3, bo3, csr1, off1, csr2, off2, csr3, off3);

  // input projections (coalesced LDS-transposed x, LDS weights)
  proj_both_kernel<<<SB2_STAY + SB2_PAT, 512, 0, stream>>>(
      x_stay, fWpS, bp_stay, x_pat, fWpP, bp_pat, hs0, hp0);

  for (int l = 0; l < 2; ++l) {
    ushort_t* fWl0 = fWlB + (size_t)(l * 3 + 0) * 8192;
    ushort_t* fWl1 = fWlB + (size_t)(l * 3 + 1) * 8192;
    ushort_t* fWl2 = fWlB + (size_t)(l * 3 + 2) * 8192;
    ushort_t* fWr0 = fWrB + (size_t)(l * 3 + 0) * 8192;
    ushort_t* fWr1 = fWrB + (size_t)(l * 3 + 1) * 8192;
    ushort_t* fWr2 = fWrB + (size_t)(l * 3 + 2) * 8192;
    const float* bl0 = bl + (size_t)(l * 3 + 0) * H;
    const float* bl1 = bl + (size_t)(l * 3 + 1) * H;
    const float* bl2 = bl + (size_t)(l * 3 + 2) * H;
    const float* g  = ln_g + (size_t)l * H;
    const float* bb = ln_b + (size_t)l * H;

    const ushort_t* hin_s = (l == 0) ? hs0 : hs1;
    const ushort_t* hin_p = (l == 0) ? hp0 : hp1;
    ushort_t* hout_s = (l == 0) ? hs1 : hs0;
    ushort_t* hout_p = (l == 0) ? hp1 : hp0;

    // final layer: pat side is dead (reference never consumes final hp)
    const int blocks = (l == 1) ? SB2_STAY : (SB2_STAY + SB2_PAT);
    sage_fused_mfma<<<blocks, 512, 0, stream>>>(
        hin_s, hin_p, off1, csr1, off2, csr2, off3, csr3,
        fWl0, fWr0, fWl1, fWr1, fWl2, fWr2,
        bl0, bl1, bl2, g, bb,
        hout_p, hout_s, Wreg, breg, out, (l == 1) ? 1 : 0);
  }
}